// Round 2
// baseline (2861.359 us; speedup 1.0000x reference)
//
#include <hip/hip_runtime.h>
#include <hip/hip_bf16.h>

typedef __attribute__((ext_vector_type(8))) short short8;
typedef __attribute__((ext_vector_type(4))) float floatx4;

#define BM 128
#define BN 128
#define BK 64
#define LDS_PAD 24
#define LDS_STRIDE (BK + LDS_PAD)  // 88 elems = 176B rows: 16B-aligned, 12-bank rotation -> only 2-way aliasing (free)

// C[m,n] = sum_k A[m*lda + k] * W[n*ldw + k]   (einsum 'mk,nk->mn')
// A is bf16 (internal workspace), W is f32 (raw input weights, converted to bf16 while staging to LDS).
// Grid: (M/128, ceil(N/128)). M multiple of 128; K multiple of 64; N arbitrary (guarded).
template <typename OUT_T>
__global__ __launch_bounds__(256) void gemm_bt(
    const __hip_bfloat16* __restrict__ A, const float* __restrict__ W,
    OUT_T* __restrict__ C,
    int N, int K, int lda, int ldw, int ldc)
{
    __shared__ __align__(16) __hip_bfloat16 As[BM * LDS_STRIDE];
    __shared__ __align__(16) __hip_bfloat16 Ws[BN * LDS_STRIDE];
    const int tid  = threadIdx.x;
    const int bm   = blockIdx.x * BM;
    const int bn   = blockIdx.y * BN;
    const int lane = tid & 63;
    const int wid  = tid >> 6;
    const int wm   = (wid >> 1) * 64;
    const int wn   = (wid & 1) * 64;
    const int l15  = lane & 15;
    const int quad = lane >> 4;

    floatx4 acc[4][4];
#pragma unroll
    for (int i = 0; i < 4; ++i)
#pragma unroll
        for (int j = 0; j < 4; ++j)
#pragma unroll
            for (int r = 0; r < 4; ++r) acc[i][j][r] = 0.f;

    const int lrow = tid >> 3;       // 0..31
    const int lcol = (tid & 7) * 8;  // 0,8,..,56

    for (int k0 = 0; k0 < K; k0 += BK) {
#pragma unroll
        for (int r = 0; r < 4; ++r) {
            const int row = r * 32 + lrow;
            const uint4 va = *reinterpret_cast<const uint4*>(A + (size_t)(bm + row) * lda + k0 + lcol);
            *reinterpret_cast<uint4*>(&As[row * LDS_STRIDE + lcol]) = va;
            const int n = bn + row;
            __align__(16) __hip_bfloat16 wb[8];
            if (n < N) {
                const float4 f0 = *reinterpret_cast<const float4*>(W + (size_t)n * ldw + k0 + lcol);
                const float4 f1 = *reinterpret_cast<const float4*>(W + (size_t)n * ldw + k0 + lcol + 4);
                wb[0] = __float2bfloat16(f0.x); wb[1] = __float2bfloat16(f0.y);
                wb[2] = __float2bfloat16(f0.z); wb[3] = __float2bfloat16(f0.w);
                wb[4] = __float2bfloat16(f1.x); wb[5] = __float2bfloat16(f1.y);
                wb[6] = __float2bfloat16(f1.z); wb[7] = __float2bfloat16(f1.w);
            } else {
#pragma unroll
                for (int j = 0; j < 8; ++j) wb[j] = __float2bfloat16(0.f);
            }
            *reinterpret_cast<uint4*>(&Ws[row * LDS_STRIDE + lcol]) = *reinterpret_cast<const uint4*>(wb);
        }
        __syncthreads();
#pragma unroll
        for (int kk = 0; kk < BK; kk += 32) {
            short8 af[4], bfr[4];
#pragma unroll
            for (int i = 0; i < 4; ++i)
                af[i] = *reinterpret_cast<const short8*>(&As[(wm + i * 16 + l15) * LDS_STRIDE + kk + quad * 8]);
#pragma unroll
            for (int j = 0; j < 4; ++j)
                bfr[j] = *reinterpret_cast<const short8*>(&Ws[(wn + j * 16 + l15) * LDS_STRIDE + kk + quad * 8]);
#pragma unroll
            for (int i = 0; i < 4; ++i)
#pragma unroll
                for (int j = 0; j < 4; ++j)
                    acc[i][j] = __builtin_amdgcn_mfma_f32_16x16x32_bf16(af[i], bfr[j], acc[i][j], 0, 0, 0);
        }
        __syncthreads();
    }

#pragma unroll
    for (int i = 0; i < 4; ++i) {
#pragma unroll
        for (int j = 0; j < 4; ++j) {
            const int col = bn + wn + j * 16 + l15;
            if (col < N) {
#pragma unroll
                for (int r = 0; r < 4; ++r) {
                    const int rowg = bm + wm + i * 16 + quad * 4 + r;
                    if constexpr (sizeof(OUT_T) == 4)
                        C[(size_t)rowg * ldc + col] = acc[i][j][r];
                    else
                        C[(size_t)rowg * ldc + col] = __float2bfloat16(acc[i][j][r]);
                }
            }
        }
    }
}

// LayerNorm over D_MODEL=1024 per token (f32 in -> bf16 h) + exact f32 residual copy.
__global__ __launch_bounds__(256) void ln_res_kernel(
    const float* __restrict__ x,
    const float* __restrict__ nw, const float* __restrict__ nb,
    __hip_bfloat16* __restrict__ h, float* __restrict__ res)
{
    const int row = blockIdx.x;
    const int tid = threadIdx.x;
    const float* xr = x + (size_t)row * 1024;
    float v[4];
    float sum = 0.f, sumsq = 0.f;
#pragma unroll
    for (int i = 0; i < 4; ++i) {
        const float f = xr[tid + i * 256];
        v[i] = f; sum += f; sumsq += f * f;
    }
#pragma unroll
    for (int off = 32; off > 0; off >>= 1) {
        sum   += __shfl_down(sum, off);
        sumsq += __shfl_down(sumsq, off);
    }
    __shared__ float ssum[4], ssq[4];
    const int w = tid >> 6, lane = tid & 63;
    if (lane == 0) { ssum[w] = sum; ssq[w] = sumsq; }
    __syncthreads();
    sum   = ssum[0] + ssum[1] + ssum[2] + ssum[3];
    sumsq = ssq[0] + ssq[1] + ssq[2] + ssq[3];
    const float mu  = sum * (1.f / 1024.f);
    const float var = sumsq * (1.f / 1024.f) - mu * mu;
    const float rs  = rsqrtf(var + 1e-5f);
#pragma unroll
    for (int i = 0; i < 4; ++i) {
        const int c = tid + i * 256;
        const float hn = (v[i] - mu) * rs * nw[c] + nb[c];
        h[(size_t)row * 1024 + c]   = __float2bfloat16(hn);
        res[(size_t)row * 1024 + c] = v[i];
    }
}

// Depthwise causal conv (width 4) + bias + SiLU.  xin = xz[:, 0:2048].
__global__ __launch_bounds__(256) void conv_silu_kernel(
    const __hip_bfloat16* __restrict__ xz,
    const float* __restrict__ conv_w, const float* __restrict__ conv_b,
    __hip_bfloat16* __restrict__ u)
{
    const int idx = blockIdx.x * 256 + threadIdx.x;   // over B*L*2048 = 8388608
    const int d   = idx & 2047;
    const int row = idx >> 11;        // b*L + l
    const int b   = row >> 11;
    const int l   = row & 2047;
    float acc = conv_b[d];
#pragma unroll
    for (int j = 0; j < 4; ++j) {
        const int ls = l - 3 + j;
        if (ls >= 0)
            acc += __bfloat162float(xz[(size_t)(b * 2048 + ls) * 4096 + d]) * conv_w[d * 4 + j];
    }
    const float s = acc / (1.f + __expf(-acc));
    u[(size_t)row * 2048 + d] = __float2bfloat16(s);
}

// Selective scan. 16 lanes per channel (one lane per state s).
// block: 256 threads = 16 channels; grid: 256 blocks (= B * D_INNER / 16).
// NOTE: y may alias dt_pre (same-index read-before-write within one wave) -> no restrict on those.
__global__ __launch_bounds__(256) void scan_kernel(
    const __hip_bfloat16* dt_pre,               // [B*L, 2048] pre-softplus, pre-bias
    const __hip_bfloat16* __restrict__ u,       // [B*L, 2048]
    const __hip_bfloat16* __restrict__ xdbl,    // [B*L, 96]  (cols 64..79 = B, 80..95 = C)
    const __hip_bfloat16* __restrict__ xz,      // [B*L, 4096] (cols 2048.. = z)
    const float* __restrict__ A_log,            // [2048, 16]
    const float* __restrict__ Dw,               // [2048]
    const float* __restrict__ dt_bias,          // [2048]
    __hip_bfloat16* y)                          // [B*L, 2048]
{
    const int tid = threadIdx.x;
    const int s   = tid & 15;
    const int g   = tid >> 4;
    const int blk = blockIdx.x;
    const int b   = blk >> 7;                 // 128 blocks per batch
    const int d   = (blk & 127) * 16 + g;

    const float As   = -__expf(A_log[d * 16 + s]);
    const float bias = dt_bias[d];
    const float Dv   = Dw[d];
    float state = 0.f;
    const int rowbase = b * 2048;

    for (int l = 0; l < 2048; ++l) {
        const size_t row = (size_t)(rowbase + l);
        const float dtp = __bfloat162float(dt_pre[row * 2048 + d]) + bias;
        const float dt  = (dtp > 20.f) ? dtp : log1pf(__expf(dtp));
        const float uu  = __bfloat162float(u[row * 2048 + d]);
        const float Bv  = __bfloat162float(xdbl[row * 96 + 64 + s]);
        const float Cv  = __bfloat162float(xdbl[row * 96 + 80 + s]);
        const float dA  = __expf(dt * As);
        state = dA * state + (dt * uu) * Bv;
        float py = state * Cv;
        py += __shfl_xor(py, 1);
        py += __shfl_xor(py, 2);
        py += __shfl_xor(py, 4);
        py += __shfl_xor(py, 8);
        if (s == 0) {
            const float zv = __bfloat162float(xz[row * 4096 + 2048 + d]);
            const float sz = zv / (1.f + __expf(-zv));
            const float yy = (py + uu * Dv) * sz;
            y[row * 2048 + d] = __float2bfloat16(yy);
        }
    }
}

extern "C" void kernel_launch(void* const* d_in, const int* in_sizes, int n_in,
                              void* d_out, int out_size, void* d_ws, size_t ws_size,
                              hipStream_t stream)
{
    const float* x          = (const float*)d_in[0];
    const float* in_proj_w  = (const float*)d_in[1];
    const float* conv_w     = (const float*)d_in[2];
    const float* conv_b     = (const float*)d_in[3];
    const float* x_proj_w   = (const float*)d_in[4];
    const float* dt_proj_w  = (const float*)d_in[5];
    const float* dt_proj_b  = (const float*)d_in[6];
    const float* A_log      = (const float*)d_in[7];
    const float* Dw         = (const float*)d_in[8];
    const float* out_proj_w = (const float*)d_in[9];
    const float* norm_w     = (const float*)d_in[10];
    const float* norm_b     = (const float*)d_in[11];

    float* out = (float*)d_out;                 // [4096,1024] f32, then residual [4096,1024] f32
    float* res = out + 4194304;
    char* ws = (char*)d_ws;
    __hip_bfloat16* h      = (__hip_bfloat16*)(ws);                     // 4096x1024 bf16
    __hip_bfloat16* xz     = (__hip_bfloat16*)(ws + 8388608);           // 4096x4096 bf16
    __hip_bfloat16* u      = (__hip_bfloat16*)(ws + 41943040);          // 4096x2048 bf16
    __hip_bfloat16* xdbl   = (__hip_bfloat16*)(ws + 58720256);          // 4096x96  bf16
    __hip_bfloat16* dtpre  = (__hip_bfloat16*)(ws + 59506688);          // 4096x2048 bf16 (y aliases this)
    __hip_bfloat16* y      = dtpre;                                     // alias: safe, see scan_kernel

    // 1. LayerNorm + residual copy
    ln_res_kernel<<<4096, 256, 0, stream>>>(x, norm_w, norm_b, h, res);
    // 2. xz = h @ in_proj_w^T   (M=4096, N=4096, K=1024)
    gemm_bt<__hip_bfloat16><<<dim3(32, 32), 256, 0, stream>>>(h, in_proj_w, xz, 4096, 1024, 1024, 1024, 4096);
    // 3. u = silu(depthwise_conv(xin) + conv_b)
    conv_silu_kernel<<<32768, 256, 0, stream>>>(xz, conv_w, conv_b, u);
    // 4. x_dbl = u @ x_proj_w^T  (M=4096, N=96, K=2048)
    gemm_bt<__hip_bfloat16><<<dim3(32, 1), 256, 0, stream>>>(u, x_proj_w, xdbl, 96, 2048, 2048, 2048, 96);
    // 5. dt_pre = dt_low @ dt_proj_w^T  (M=4096, N=2048, K=64); bias+softplus fused into scan
    gemm_bt<__hip_bfloat16><<<dim3(32, 16), 256, 0, stream>>>(xdbl, dt_proj_w, dtpre, 2048, 64, 96, 64, 2048);
    // 6. selective scan + skip + gate (y aliases dtpre)
    scan_kernel<<<256, 256, 0, stream>>>(dtpre, u, xdbl, xz, A_log, Dw, dt_proj_b, y);
    // 7. out = y @ out_proj_w^T  (M=4096, N=1024, K=2048) -> f32 output
    gemm_bt<float><<<dim3(32, 8), 256, 0, stream>>>(y, out_proj_w, out, 1024, 2048, 2048, 2048, 1024);
}

// Round 3
// 769.002 us; speedup vs baseline: 3.7209x; 3.7209x over previous
//
#include <hip/hip_runtime.h>
#include <hip/hip_bf16.h>

typedef __attribute__((ext_vector_type(8))) short short8;
typedef __attribute__((ext_vector_type(4))) float floatx4;

#define BM 128
#define BN 128
#define BK 64
#define LDS_PAD 24
#define LDS_STRIDE (BK + LDS_PAD)  // 88 elems = 176B rows: 16B-aligned, 12-bank rotation -> only 2-way aliasing (free)

#define G_CHUNKS 8
#define T_CHUNK 256   // 2048 / G_CHUNKS

// C[m,n] = sum_k A[m*lda + k] * W[n*ldw + k]   (einsum 'mk,nk->mn')
// A bf16 workspace; W f32 input weights (converted to bf16 during LDS staging).
// SOFTPLUS epilogue: out = softplus(acc + bias[col]).
template <typename OUT_T, bool SOFTPLUS>
__global__ __launch_bounds__(256) void gemm_bt(
    const __hip_bfloat16* __restrict__ A, const float* __restrict__ W,
    OUT_T* __restrict__ C, const float* __restrict__ bias,
    int N, int K, int lda, int ldw, int ldc)
{
    __shared__ __align__(16) __hip_bfloat16 As[BM * LDS_STRIDE];
    __shared__ __align__(16) __hip_bfloat16 Ws[BN * LDS_STRIDE];
    const int tid  = threadIdx.x;
    const int bm   = blockIdx.x * BM;
    const int bn   = blockIdx.y * BN;
    const int lane = tid & 63;
    const int wid  = tid >> 6;
    const int wm   = (wid >> 1) * 64;
    const int wn   = (wid & 1) * 64;
    const int l15  = lane & 15;
    const int quad = lane >> 4;

    floatx4 acc[4][4];
#pragma unroll
    for (int i = 0; i < 4; ++i)
#pragma unroll
        for (int j = 0; j < 4; ++j)
#pragma unroll
            for (int r = 0; r < 4; ++r) acc[i][j][r] = 0.f;

    const int lrow = tid >> 3;       // 0..31
    const int lcol = (tid & 7) * 8;  // 0,8,..,56

    for (int k0 = 0; k0 < K; k0 += BK) {
#pragma unroll
        for (int r = 0; r < 4; ++r) {
            const int row = r * 32 + lrow;
            const uint4 va = *reinterpret_cast<const uint4*>(A + (size_t)(bm + row) * lda + k0 + lcol);
            *reinterpret_cast<uint4*>(&As[row * LDS_STRIDE + lcol]) = va;
            const int n = bn + row;
            __align__(16) __hip_bfloat16 wb[8];
            if (n < N) {
                const float4 f0 = *reinterpret_cast<const float4*>(W + (size_t)n * ldw + k0 + lcol);
                const float4 f1 = *reinterpret_cast<const float4*>(W + (size_t)n * ldw + k0 + lcol + 4);
                wb[0] = __float2bfloat16(f0.x); wb[1] = __float2bfloat16(f0.y);
                wb[2] = __float2bfloat16(f0.z); wb[3] = __float2bfloat16(f0.w);
                wb[4] = __float2bfloat16(f1.x); wb[5] = __float2bfloat16(f1.y);
                wb[6] = __float2bfloat16(f1.z); wb[7] = __float2bfloat16(f1.w);
            } else {
#pragma unroll
                for (int j = 0; j < 8; ++j) wb[j] = __float2bfloat16(0.f);
            }
            *reinterpret_cast<uint4*>(&Ws[row * LDS_STRIDE + lcol]) = *reinterpret_cast<const uint4*>(wb);
        }
        __syncthreads();
#pragma unroll
        for (int kk = 0; kk < BK; kk += 32) {
            short8 af[4], bfr[4];
#pragma unroll
            for (int i = 0; i < 4; ++i)
                af[i] = *reinterpret_cast<const short8*>(&As[(wm + i * 16 + l15) * LDS_STRIDE + kk + quad * 8]);
#pragma unroll
            for (int j = 0; j < 4; ++j)
                bfr[j] = *reinterpret_cast<const short8*>(&Ws[(wn + j * 16 + l15) * LDS_STRIDE + kk + quad * 8]);
#pragma unroll
            for (int i = 0; i < 4; ++i)
#pragma unroll
                for (int j = 0; j < 4; ++j)
                    acc[i][j] = __builtin_amdgcn_mfma_f32_16x16x32_bf16(af[i], bfr[j], acc[i][j], 0, 0, 0);
        }
        __syncthreads();
    }

#pragma unroll
    for (int i = 0; i < 4; ++i) {
#pragma unroll
        for (int j = 0; j < 4; ++j) {
            const int col = bn + wn + j * 16 + l15;
            if (col < N) {
                float bv = 0.f;
                if constexpr (SOFTPLUS) bv = bias[col];
#pragma unroll
                for (int r = 0; r < 4; ++r) {
                    const int rowg = bm + wm + i * 16 + quad * 4 + r;
                    float v = acc[i][j][r];
                    if constexpr (SOFTPLUS) {
                        v += bv;
                        v = (v > 20.f) ? v : log1pf(__expf(v));
                    }
                    if constexpr (sizeof(OUT_T) == 4)
                        C[(size_t)rowg * ldc + col] = v;
                    else
                        C[(size_t)rowg * ldc + col] = __float2bfloat16(v);
                }
            }
        }
    }
}

// LayerNorm over D_MODEL=1024 per token (f32 in -> bf16 h) + exact f32 residual copy.
__global__ __launch_bounds__(256) void ln_res_kernel(
    const float* __restrict__ x,
    const float* __restrict__ nw, const float* __restrict__ nb,
    __hip_bfloat16* __restrict__ h, float* __restrict__ res)
{
    const int row = blockIdx.x;
    const int tid = threadIdx.x;
    const float* xr = x + (size_t)row * 1024;
    float v[4];
    float sum = 0.f, sumsq = 0.f;
#pragma unroll
    for (int i = 0; i < 4; ++i) {
        const float f = xr[tid + i * 256];
        v[i] = f; sum += f; sumsq += f * f;
    }
#pragma unroll
    for (int off = 32; off > 0; off >>= 1) {
        sum   += __shfl_down(sum, off);
        sumsq += __shfl_down(sumsq, off);
    }
    __shared__ float ssum[4], ssq[4];
    const int w = tid >> 6, lane = tid & 63;
    if (lane == 0) { ssum[w] = sum; ssq[w] = sumsq; }
    __syncthreads();
    sum   = ssum[0] + ssum[1] + ssum[2] + ssum[3];
    sumsq = ssq[0] + ssq[1] + ssq[2] + ssq[3];
    const float mu  = sum * (1.f / 1024.f);
    const float var = sumsq * (1.f / 1024.f) - mu * mu;
    const float rs  = rsqrtf(var + 1e-5f);
#pragma unroll
    for (int i = 0; i < 4; ++i) {
        const int c = tid + i * 256;
        const float hn = (v[i] - mu) * rs * nw[c] + nb[c];
        h[(size_t)row * 1024 + c]   = __float2bfloat16(hn);
        res[(size_t)row * 1024 + c] = v[i];
    }
}

// Depthwise causal conv (width 4) + bias + SiLU.  xin = xz[:, 0:2048].
__global__ __launch_bounds__(256) void conv_silu_kernel(
    const __hip_bfloat16* __restrict__ xz,
    const float* __restrict__ conv_w, const float* __restrict__ conv_b,
    __hip_bfloat16* __restrict__ u)
{
    const int idx = blockIdx.x * 256 + threadIdx.x;   // over B*L*2048 = 8388608
    const int d   = idx & 2047;
    const int row = idx >> 11;        // b*L + l
    const int b   = row >> 11;
    const int l   = row & 2047;
    float acc = conv_b[d];
#pragma unroll
    for (int j = 0; j < 4; ++j) {
        const int ls = l - 3 + j;
        if (ls >= 0)
            acc += __bfloat162float(xz[(size_t)(b * 2048 + ls) * 4096 + d]) * conv_w[d * 4 + j];
    }
    const float s = acc / (1.f + __expf(-acc));
    u[(size_t)row * 2048 + d] = __float2bfloat16(s);
}

// ---- Chunked linear scan: h_l = dA_l*h_{l-1} + dt_l*u_l*B_l (linear -> associative) ----
// Lane mapping (all phases): s = tid&15 (state), g = tid>>4 (channel-in-block).
// blockIdx.x = c*256 + cb; cb -> (b, d) as in round 2; c = time chunk.

// Phase 1: per-chunk cumulative decay P = prod dA and local scan S (from h=0).
__global__ __launch_bounds__(256) void scan_phase1(
    const __hip_bfloat16* __restrict__ dt,     // [4096,2048] post-softplus
    const __hip_bfloat16* __restrict__ u,
    const __hip_bfloat16* __restrict__ xdbl,   // cols 64..79 = B
    const float* __restrict__ A_log,
    float* __restrict__ Pbuf, float* __restrict__ Sbuf)  // [65536 * G_CHUNKS]
{
    const int tid = threadIdx.x;
    const int s   = tid & 15;
    const int g   = tid >> 4;
    const int cb  = blockIdx.x & 255;
    const int c   = blockIdx.x >> 8;
    const int b   = cb >> 7;
    const int d   = (cb & 127) * 16 + g;

    const float As = -__expf(A_log[d * 16 + s]);
    float P = 1.f, S = 0.f;
    const int rowbase = b * 2048 + c * T_CHUNK;
    for (int l = 0; l < T_CHUNK; ++l) {
        const size_t row = (size_t)(rowbase + l);
        const float dtv = __bfloat162float(dt[row * 2048 + d]);
        const float uu  = __bfloat162float(u[row * 2048 + d]);
        const float Bv  = __bfloat162float(xdbl[row * 96 + 64 + s]);
        const float dA  = __expf(dtv * As);
        P *= dA;
        S = dA * S + (dtv * uu) * Bv;
    }
    const int q = ((b << 11) + d) * 16 + s;
    Pbuf[q * G_CHUNKS + c] = P;
    Sbuf[q * G_CHUNKS + c] = S;
}

// Phase 2: serial combine across chunks (G steps), emit per-chunk initial states.
__global__ __launch_bounds__(256) void scan_phase2(
    const float* __restrict__ Pbuf, const float* __restrict__ Sbuf,
    float* __restrict__ Hinit)
{
    const int q = blockIdx.x * 256 + threadIdx.x;   // 65536 sequences
    float h = 0.f;
#pragma unroll
    for (int c = 0; c < G_CHUNKS; ++c) {
        Hinit[q * G_CHUNKS + c] = h;
        h = Pbuf[q * G_CHUNKS + c] * h + Sbuf[q * G_CHUNKS + c];
    }
}

// Phase 3: re-run chunk from Hinit, emit y = (sum_s h*C + u*D) * silu(z).
// y may alias dt (same-index read precedes write within the wave) -> no restrict on those.
__global__ __launch_bounds__(256) void scan_phase3(
    const __hip_bfloat16* dt,
    const __hip_bfloat16* __restrict__ u,
    const __hip_bfloat16* __restrict__ xdbl,   // cols 64..79 = B, 80..95 = C
    const __hip_bfloat16* __restrict__ xz,     // cols 2048.. = z
    const float* __restrict__ A_log,
    const float* __restrict__ Dw,
    const float* __restrict__ Hinit,
    __hip_bfloat16* y)
{
    const int tid = threadIdx.x;
    const int s   = tid & 15;
    const int g   = tid >> 4;
    const int cb  = blockIdx.x & 255;
    const int c   = blockIdx.x >> 8;
    const int b   = cb >> 7;
    const int d   = (cb & 127) * 16 + g;

    const float As = -__expf(A_log[d * 16 + s]);
    const float Dv = Dw[d];
    const int q = ((b << 11) + d) * 16 + s;
    float h = Hinit[q * G_CHUNKS + c];
    const int rowbase = b * 2048 + c * T_CHUNK;

    for (int l = 0; l < T_CHUNK; ++l) {
        const size_t row = (size_t)(rowbase + l);
        const float dtv = __bfloat162float(dt[row * 2048 + d]);
        const float uu  = __bfloat162float(u[row * 2048 + d]);
        const float Bv  = __bfloat162float(xdbl[row * 96 + 64 + s]);
        const float Cv  = __bfloat162float(xdbl[row * 96 + 80 + s]);
        const float dA  = __expf(dtv * As);
        h = dA * h + (dtv * uu) * Bv;
        float py = h * Cv;
        py += __shfl_xor(py, 1);
        py += __shfl_xor(py, 2);
        py += __shfl_xor(py, 4);
        py += __shfl_xor(py, 8);
        if (s == 0) {
            const float zv = __bfloat162float(xz[row * 4096 + 2048 + d]);
            const float sz = zv / (1.f + __expf(-zv));
            const float yy = (py + uu * Dv) * sz;
            y[row * 2048 + d] = __float2bfloat16(yy);
        }
    }
}

extern "C" void kernel_launch(void* const* d_in, const int* in_sizes, int n_in,
                              void* d_out, int out_size, void* d_ws, size_t ws_size,
                              hipStream_t stream)
{
    const float* x          = (const float*)d_in[0];
    const float* in_proj_w  = (const float*)d_in[1];
    const float* conv_w     = (const float*)d_in[2];
    const float* conv_b     = (const float*)d_in[3];
    const float* x_proj_w   = (const float*)d_in[4];
    const float* dt_proj_w  = (const float*)d_in[5];
    const float* dt_proj_b  = (const float*)d_in[6];
    const float* A_log      = (const float*)d_in[7];
    const float* Dw         = (const float*)d_in[8];
    const float* out_proj_w = (const float*)d_in[9];
    const float* norm_w     = (const float*)d_in[10];
    const float* norm_b     = (const float*)d_in[11];

    float* out = (float*)d_out;                 // [4096,1024] f32, then residual [4096,1024] f32
    float* res = out + 4194304;
    char* ws = (char*)d_ws;
    __hip_bfloat16* h      = (__hip_bfloat16*)(ws);                     // 4096x1024 bf16 (dead after gemm1)
    __hip_bfloat16* xz     = (__hip_bfloat16*)(ws + 8388608);           // 4096x4096 bf16
    __hip_bfloat16* u      = (__hip_bfloat16*)(ws + 41943040);          // 4096x2048 bf16
    __hip_bfloat16* xdbl   = (__hip_bfloat16*)(ws + 58720256);          // 4096x96  bf16
    __hip_bfloat16* dtbuf  = (__hip_bfloat16*)(ws + 59506688);          // 4096x2048 bf16 (y aliases this)
    __hip_bfloat16* y      = dtbuf;                                     // alias: safe, see scan_phase3
    // scan scratch reuses the retired h region (h consumed by gemm1 long before phase 1)
    float* Pbuf  = (float*)(ws);              // 65536*8*4 = 2 MB
    float* Sbuf  = (float*)(ws + 2097152);    // 2 MB
    float* Hinit = (float*)(ws + 4194304);    // 2 MB

    // 1. LayerNorm + residual copy
    ln_res_kernel<<<4096, 256, 0, stream>>>(x, norm_w, norm_b, h, res);
    // 2. xz = h @ in_proj_w^T   (M=4096, N=4096, K=1024)
    gemm_bt<__hip_bfloat16, false><<<dim3(32, 32), 256, 0, stream>>>(h, in_proj_w, xz, nullptr, 4096, 1024, 1024, 1024, 4096);
    // 3. u = silu(depthwise_conv(xin) + conv_b)
    conv_silu_kernel<<<32768, 256, 0, stream>>>(xz, conv_w, conv_b, u);
    // 4. x_dbl = u @ x_proj_w^T  (M=4096, N=96, K=2048)
    gemm_bt<__hip_bfloat16, false><<<dim3(32, 1), 256, 0, stream>>>(u, x_proj_w, xdbl, nullptr, 96, 2048, 2048, 2048, 96);
    // 5. dt = softplus(dt_low @ dt_proj_w^T + dt_b)  (M=4096, N=2048, K=64), fused epilogue
    gemm_bt<__hip_bfloat16, true><<<dim3(32, 16), 256, 0, stream>>>(xdbl, dt_proj_w, dtbuf, dt_proj_b, 2048, 64, 96, 64, 2048);
    // 6. chunked selective scan
    scan_phase1<<<256 * G_CHUNKS, 256, 0, stream>>>(dtbuf, u, xdbl, A_log, Pbuf, Sbuf);
    scan_phase2<<<256, 256, 0, stream>>>(Pbuf, Sbuf, Hinit);
    scan_phase3<<<256 * G_CHUNKS, 256, 0, stream>>>(dtbuf, u, xdbl, xz, A_log, Dw, Hinit, y);
    // 7. out = y @ out_proj_w^T  (M=4096, N=1024, K=2048) -> f32 output
    gemm_bt<float, false><<<dim3(32, 8), 256, 0, stream>>>(y, out_proj_w, out, nullptr, 1024, 2048, 2048, 2048, 1024);
}

// Round 4
// 541.151 us; speedup vs baseline: 5.2875x; 1.4210x over previous
//
#include <hip/hip_runtime.h>
#include <hip/hip_bf16.h>

typedef __attribute__((ext_vector_type(8))) short short8;
typedef __attribute__((ext_vector_type(4))) float floatx4;

#define BM 128
#define BN 128
#define BK 64
#define LDS_PAD 24
#define LDS_STRIDE (BK + LDS_PAD)

#define G_CHUNKS 8
#define T_CHUNK 256

__device__ __forceinline__ float bf2f(short v) {
    return __builtin_bit_cast(float, ((unsigned)(unsigned short)v) << 16);
}
__device__ __forceinline__ unsigned short f2bfbits(float f) {
    return __builtin_bit_cast(unsigned short, __float2bfloat16(f));
}
// 16-lane (DPP row) rotate-reduce sum: every lane of each 16-lane row ends with the row sum.
__device__ __forceinline__ float row16_sum(float v) {
    v += __builtin_bit_cast(float, __builtin_amdgcn_update_dpp(0, __builtin_bit_cast(int, v), 0x121, 0xf, 0xf, true));
    v += __builtin_bit_cast(float, __builtin_amdgcn_update_dpp(0, __builtin_bit_cast(int, v), 0x122, 0xf, 0xf, true));
    v += __builtin_bit_cast(float, __builtin_amdgcn_update_dpp(0, __builtin_bit_cast(int, v), 0x124, 0xf, 0xf, true));
    v += __builtin_bit_cast(float, __builtin_amdgcn_update_dpp(0, __builtin_bit_cast(int, v), 0x128, 0xf, 0xf, true));
    return v;
}

// ---------------- GEMM (plain): C[m,n] = sum_k A[m,k]*W[n,k], A bf16, W f32 staged->bf16 ----------------
template <typename OUT_T>
__global__ __launch_bounds__(256) void gemm_bt(
    const __hip_bfloat16* __restrict__ A, const float* __restrict__ W,
    OUT_T* __restrict__ C, int N, int K, int lda, int ldw, int ldc)
{
    __shared__ __align__(16) __hip_bfloat16 As[BM * LDS_STRIDE];
    __shared__ __align__(16) __hip_bfloat16 Ws[BN * LDS_STRIDE];
    const int tid  = threadIdx.x;
    const int bm   = blockIdx.x * BM;
    const int bn   = blockIdx.y * BN;
    const int lane = tid & 63;
    const int wid  = tid >> 6;
    const int wm   = (wid >> 1) * 64;
    const int wn   = (wid & 1) * 64;
    const int l15  = lane & 15;
    const int quad = lane >> 4;

    floatx4 acc[4][4];
#pragma unroll
    for (int i = 0; i < 4; ++i)
#pragma unroll
        for (int j = 0; j < 4; ++j)
#pragma unroll
            for (int r = 0; r < 4; ++r) acc[i][j][r] = 0.f;

    const int lrow = tid >> 3;
    const int lcol = (tid & 7) * 8;

    for (int k0 = 0; k0 < K; k0 += BK) {
#pragma unroll
        for (int r = 0; r < 4; ++r) {
            const int row = r * 32 + lrow;
            const uint4 va = *reinterpret_cast<const uint4*>(A + (size_t)(bm + row) * lda + k0 + lcol);
            *reinterpret_cast<uint4*>(&As[row * LDS_STRIDE + lcol]) = va;
            const int n = bn + row;
            __align__(16) unsigned short wb[8];
            const float4 f0 = *reinterpret_cast<const float4*>(W + (size_t)n * ldw + k0 + lcol);
            const float4 f1 = *reinterpret_cast<const float4*>(W + (size_t)n * ldw + k0 + lcol + 4);
            wb[0] = f2bfbits(f0.x); wb[1] = f2bfbits(f0.y);
            wb[2] = f2bfbits(f0.z); wb[3] = f2bfbits(f0.w);
            wb[4] = f2bfbits(f1.x); wb[5] = f2bfbits(f1.y);
            wb[6] = f2bfbits(f1.z); wb[7] = f2bfbits(f1.w);
            *reinterpret_cast<uint4*>(&Ws[row * LDS_STRIDE + lcol]) = *reinterpret_cast<const uint4*>(wb);
        }
        __syncthreads();
#pragma unroll
        for (int kk = 0; kk < BK; kk += 32) {
            short8 af[4], bfr[4];
#pragma unroll
            for (int i = 0; i < 4; ++i)
                af[i] = *reinterpret_cast<const short8*>(&As[(wm + i * 16 + l15) * LDS_STRIDE + kk + quad * 8]);
#pragma unroll
            for (int j = 0; j < 4; ++j)
                bfr[j] = *reinterpret_cast<const short8*>(&Ws[(wn + j * 16 + l15) * LDS_STRIDE + kk + quad * 8]);
#pragma unroll
            for (int i = 0; i < 4; ++i)
#pragma unroll
                for (int j = 0; j < 4; ++j)
                    acc[i][j] = __builtin_amdgcn_mfma_f32_16x16x32_bf16(af[i], bfr[j], acc[i][j], 0, 0, 0);
        }
        __syncthreads();
    }

#pragma unroll
    for (int i = 0; i < 4; ++i) {
#pragma unroll
        for (int j = 0; j < 4; ++j) {
            const int col = bn + wn + j * 16 + l15;
#pragma unroll
            for (int r = 0; r < 4; ++r) {
                const int rowg = bm + wm + i * 16 + quad * 4 + r;
                if constexpr (sizeof(OUT_T) == 4)
                    C[(size_t)rowg * ldc + col] = acc[i][j][r];
                else
                    C[(size_t)rowg * ldc + col] = __float2bfloat16(acc[i][j][r]);
            }
        }
    }
}

// ---------------- dt GEMM: A from transposed layout AT[96,4096] (rows 0..63), softplus, output dtT[2048,4096] ----------------
__global__ __launch_bounds__(256) void gemm_dt(
    const __hip_bfloat16* __restrict__ AT, const float* __restrict__ W,
    const float* __restrict__ bias, __hip_bfloat16* __restrict__ CT)
{
    __shared__ __align__(16) __hip_bfloat16 As[BM * LDS_STRIDE];
    __shared__ __align__(16) __hip_bfloat16 Ws[BN * LDS_STRIDE];
    const int tid  = threadIdx.x;
    const int bm   = blockIdx.x * BM;
    const int bn   = blockIdx.y * BN;
    const int lane = tid & 63;
    const int wid  = tid >> 6;
    const int wm   = (wid >> 1) * 64;
    const int wn   = (wid & 1) * 64;
    const int l15  = lane & 15;
    const int quad = lane >> 4;

    // stage A (transposed source): As[m][k] <- AT[k*4096 + bm + m]
    {
        const int kk = tid >> 4;          // 0..15
        const int mc = (tid & 15) * 8;    // 0..120
#pragma unroll
        for (int p = 0; p < 4; ++p) {
            const int k = kk + p * 16;
            const short8 v = *reinterpret_cast<const short8*>(AT + (size_t)k * 4096 + bm + mc);
#pragma unroll
            for (int e = 0; e < 8; ++e)
                As[(mc + e) * LDS_STRIDE + k] = __builtin_bit_cast(__hip_bfloat16, (unsigned short)v[e]);
        }
    }
    // stage W (f32 -> bf16), ldw = 64
    {
        const int lrow = tid >> 3;
        const int lcol = (tid & 7) * 8;
#pragma unroll
        for (int r = 0; r < 4; ++r) {
            const int n = bn + r * 32 + lrow;
            __align__(16) unsigned short wb[8];
            const float4 f0 = *reinterpret_cast<const float4*>(W + (size_t)n * 64 + lcol);
            const float4 f1 = *reinterpret_cast<const float4*>(W + (size_t)n * 64 + lcol + 4);
            wb[0] = f2bfbits(f0.x); wb[1] = f2bfbits(f0.y);
            wb[2] = f2bfbits(f0.z); wb[3] = f2bfbits(f0.w);
            wb[4] = f2bfbits(f1.x); wb[5] = f2bfbits(f1.y);
            wb[6] = f2bfbits(f1.z); wb[7] = f2bfbits(f1.w);
            *reinterpret_cast<uint4*>(&Ws[(r * 32 + lrow) * LDS_STRIDE + lcol]) = *reinterpret_cast<const uint4*>(wb);
        }
    }
    __syncthreads();

    floatx4 acc[4][4];
#pragma unroll
    for (int i = 0; i < 4; ++i)
#pragma unroll
        for (int j = 0; j < 4; ++j)
#pragma unroll
            for (int r = 0; r < 4; ++r) acc[i][j][r] = 0.f;

#pragma unroll
    for (int kk = 0; kk < BK; kk += 32) {
        short8 af[4], bfr[4];
#pragma unroll
        for (int i = 0; i < 4; ++i)
            af[i] = *reinterpret_cast<const short8*>(&As[(wm + i * 16 + l15) * LDS_STRIDE + kk + quad * 8]);
#pragma unroll
        for (int j = 0; j < 4; ++j)
            bfr[j] = *reinterpret_cast<const short8*>(&Ws[(wn + j * 16 + l15) * LDS_STRIDE + kk + quad * 8]);
#pragma unroll
        for (int i = 0; i < 4; ++i)
#pragma unroll
            for (int j = 0; j < 4; ++j)
                acc[i][j] = __builtin_amdgcn_mfma_f32_16x16x32_bf16(af[i], bfr[j], acc[i][j], 0, 0, 0);
    }

    // epilogue: softplus(acc + bias[col]) -> dtT[col*4096 + row], packed 4 rows (8B)
#pragma unroll
    for (int i = 0; i < 4; ++i) {
#pragma unroll
        for (int j = 0; j < 4; ++j) {
            const int col = bn + wn + j * 16 + l15;
            const int rowg0 = bm + wm + i * 16 + quad * 4;
            const float bv = bias[col];
            __align__(8) unsigned short pk[4];
#pragma unroll
            for (int r = 0; r < 4; ++r) {
                float v = acc[i][j][r] + bv;
                v = (v > 20.f) ? v : log1pf(__expf(v));
                pk[r] = f2bfbits(v);
            }
            *reinterpret_cast<uint2*>(CT + (size_t)col * 4096 + rowg0) = *reinterpret_cast<const uint2*>(pk);
        }
    }
}

// ---------------- LayerNorm + residual ----------------
__global__ __launch_bounds__(256) void ln_res_kernel(
    const float* __restrict__ x,
    const float* __restrict__ nw, const float* __restrict__ nb,
    __hip_bfloat16* __restrict__ h, float* __restrict__ res)
{
    const int row = blockIdx.x;
    const int tid = threadIdx.x;
    const float* xr = x + (size_t)row * 1024;
    float v[4];
    float sum = 0.f, sumsq = 0.f;
#pragma unroll
    for (int i = 0; i < 4; ++i) {
        const float f = xr[tid + i * 256];
        v[i] = f; sum += f; sumsq += f * f;
    }
#pragma unroll
    for (int off = 32; off > 0; off >>= 1) {
        sum   += __shfl_down(sum, off);
        sumsq += __shfl_down(sumsq, off);
    }
    __shared__ float ssum[4], ssq[4];
    const int w = tid >> 6, lane = tid & 63;
    if (lane == 0) { ssum[w] = sum; ssq[w] = sumsq; }
    __syncthreads();
    sum   = ssum[0] + ssum[1] + ssum[2] + ssum[3];
    sumsq = ssq[0] + ssq[1] + ssq[2] + ssq[3];
    const float mu  = sum * (1.f / 1024.f);
    const float var = sumsq * (1.f / 1024.f) - mu * mu;
    const float rs  = rsqrtf(var + 1e-5f);
#pragma unroll
    for (int i = 0; i < 4; ++i) {
        const int c = tid + i * 256;
        const float hn = (v[i] - mu) * rs * nw[c] + nb[c];
        h[(size_t)row * 1024 + c]   = __float2bfloat16(hn);
        res[(size_t)row * 1024 + c] = v[i];
    }
}

// ---------------- conv(width4,causal)+SiLU -> uT[d,token]; silu(z) -> szT[d,token] ----------------
#define CDT 32
#define CRT 64
__global__ __launch_bounds__(256) void conv_z_kernel(
    const __hip_bfloat16* __restrict__ xz,
    const float* __restrict__ conv_w, const float* __restrict__ conv_b,
    __hip_bfloat16* __restrict__ uT, __hip_bfloat16* __restrict__ szT)
{
    __shared__ __hip_bfloat16 xin[67][CDT + 1];
    __shared__ __hip_bfloat16 zs[CRT][CDT + 1];
    const int d0 = blockIdx.x * CDT;
    const int r0 = blockIdx.y * CRT;   // global token row (tiles never cross the batch boundary: 64 | 2048)
    const int tid = threadIdx.x;
    const int l0 = r0 & 2047;
#pragma unroll
    for (int i = 0; i < 9; ++i) {
        const int idx = i * 256 + tid;
        const int r = idx >> 5, dl = idx & 31;
        if (r < 67) {
            __hip_bfloat16 v = __float2bfloat16(0.f);
            if (l0 + r - 3 >= 0) v = xz[(size_t)(r0 + r - 3) * 4096 + d0 + dl];
            xin[r][dl] = v;
        }
    }
#pragma unroll
    for (int i = 0; i < 8; ++i) {
        const int idx = i * 256 + tid;
        const int r = idx >> 5, dl = idx & 31;
        const float zv = __bfloat162float(xz[(size_t)(r0 + r) * 4096 + 2048 + d0 + dl]);
        zs[r][dl] = __float2bfloat16(zv / (1.f + __expf(-zv)));
    }
    __syncthreads();
    const int dl = tid >> 3, r8 = (tid & 7) * 8;
    const int d = d0 + dl;
    const float w0 = conv_w[d * 4 + 0], w1 = conv_w[d * 4 + 1],
                w2 = conv_w[d * 4 + 2], w3 = conv_w[d * 4 + 3];
    const float bv = conv_b[d];
    __align__(16) unsigned short ub[8], zb[8];
#pragma unroll
    for (int rr = 0; rr < 8; ++rr) {
        const int lr = r8 + rr;
        float a = fmaf(__bfloat162float(xin[lr][dl]),     w0, bv);
        a = fmaf(__bfloat162float(xin[lr + 1][dl]), w1, a);
        a = fmaf(__bfloat162float(xin[lr + 2][dl]), w2, a);
        a = fmaf(__bfloat162float(xin[lr + 3][dl]), w3, a);
        ub[rr] = f2bfbits(a / (1.f + __expf(-a)));
        zb[rr] = __builtin_bit_cast(unsigned short, zs[lr][dl]);
    }
    *reinterpret_cast<uint4*>(uT  + (size_t)d * 4096 + r0 + r8) = *reinterpret_cast<const uint4*>(ub);
    *reinterpret_cast<uint4*>(szT + (size_t)d * 4096 + r0 + r8) = *reinterpret_cast<const uint4*>(zb);
}

// ---------------- x_proj: xdblT[n,m] = sum_k uT[k,m] * W[n,k]  (n<96; W uniform -> scalar loads) ----------------
__global__ __launch_bounds__(256) void xproj_kernel(
    const __hip_bfloat16* __restrict__ uT, const float* __restrict__ W,
    __hip_bfloat16* __restrict__ xdblT)
{
    const int m  = blockIdx.y * 256 + threadIdx.x;
    const int n0 = blockIdx.x * 4;
    const float* w0 = W + (size_t)(n0 + 0) * 2048;
    const float* w1 = W + (size_t)(n0 + 1) * 2048;
    const float* w2 = W + (size_t)(n0 + 2) * 2048;
    const float* w3 = W + (size_t)(n0 + 3) * 2048;
    float a0 = 0.f, a1 = 0.f, a2 = 0.f, a3 = 0.f;
#pragma unroll 8
    for (int k = 0; k < 2048; ++k) {
        const float uv = __bfloat162float(uT[(size_t)k * 4096 + m]);
        a0 = fmaf(uv, w0[k], a0);
        a1 = fmaf(uv, w1[k], a1);
        a2 = fmaf(uv, w2[k], a2);
        a3 = fmaf(uv, w3[k], a3);
    }
    xdblT[(size_t)(n0 + 0) * 4096 + m] = __float2bfloat16(a0);
    xdblT[(size_t)(n0 + 1) * 4096 + m] = __float2bfloat16(a1);
    xdblT[(size_t)(n0 + 2) * 4096 + m] = __float2bfloat16(a2);
    xdblT[(size_t)(n0 + 3) * 4096 + m] = __float2bfloat16(a3);
}

// ---------------- chunked scan, transposed operands ----------------
__global__ __launch_bounds__(256) void scan_phase1(
    const __hip_bfloat16* __restrict__ dtT, const __hip_bfloat16* __restrict__ uT,
    const __hip_bfloat16* __restrict__ xdblT, const float* __restrict__ A_log,
    float* __restrict__ Pbuf, float* __restrict__ Sbuf)
{
    const int tid = threadIdx.x;
    const int s   = tid & 15;
    const int g   = tid >> 4;
    const int cb  = blockIdx.x & 255;
    const int c   = blockIdx.x >> 8;
    const int b   = cb >> 7;
    const int d   = (cb & 127) * 16 + g;

    const float As = -__expf(A_log[d * 16 + s]);
    const size_t base = (size_t)b * 2048 + c * T_CHUNK;
    const short8* dp = reinterpret_cast<const short8*>(dtT + (size_t)d * 4096 + base);
    const short8* up = reinterpret_cast<const short8*>(uT  + (size_t)d * 4096 + base);
    const short8* bp = reinterpret_cast<const short8*>(xdblT + (size_t)(64 + s) * 4096 + base);
    float P = 1.f, S = 0.f;
    for (int t = 0; t < T_CHUNK / 8; ++t) {
        const short8 dv = dp[t], uv = up[t], bv = bp[t];
#pragma unroll
        for (int k = 0; k < 8; ++k) {
            const float dt = bf2f(dv[k]);
            const float uu = bf2f(uv[k]);
            const float Bv = bf2f(bv[k]);
            const float dA = __expf(dt * As);
            P *= dA;
            S = fmaf(dA, S, dt * uu * Bv);
        }
    }
    const int q = ((b << 11) + d) * 16 + s;
    Pbuf[q * G_CHUNKS + c] = P;
    Sbuf[q * G_CHUNKS + c] = S;
}

__global__ __launch_bounds__(256) void scan_phase2(
    const float* __restrict__ Pbuf, const float* __restrict__ Sbuf,
    float* __restrict__ Hinit)
{
    const int q = blockIdx.x * 256 + threadIdx.x;
    float h = 0.f;
#pragma unroll
    for (int c = 0; c < G_CHUNKS; ++c) {
        Hinit[q * G_CHUNKS + c] = h;
        h = Pbuf[q * G_CHUNKS + c] * h + Sbuf[q * G_CHUNKS + c];
    }
}

__global__ __launch_bounds__(256) void scan_phase3(
    const __hip_bfloat16* __restrict__ dtT, const __hip_bfloat16* __restrict__ uT,
    const __hip_bfloat16* __restrict__ xdblT, const __hip_bfloat16* __restrict__ szT,
    const float* __restrict__ A_log, const float* __restrict__ Dw,
    const float* __restrict__ Hinit, __hip_bfloat16* __restrict__ y)
{
    const int tid = threadIdx.x;
    const int s   = tid & 15;
    const int g   = tid >> 4;
    const int cb  = blockIdx.x & 255;
    const int c   = blockIdx.x >> 8;
    const int b   = cb >> 7;
    const int d   = (cb & 127) * 16 + g;

    const float As = -__expf(A_log[d * 16 + s]);
    const float Dv = Dw[d];
    const int q = ((b << 11) + d) * 16 + s;
    float h = Hinit[q * G_CHUNKS + c];
    const size_t base = (size_t)b * 2048 + c * T_CHUNK;
    const short8* dp = reinterpret_cast<const short8*>(dtT + (size_t)d * 4096 + base);
    const short8* up = reinterpret_cast<const short8*>(uT  + (size_t)d * 4096 + base);
    const short8* bp = reinterpret_cast<const short8*>(xdblT + (size_t)(64 + s) * 4096 + base);
    const short8* cp = reinterpret_cast<const short8*>(xdblT + (size_t)(80 + s) * 4096 + base);
    const short8* zp = reinterpret_cast<const short8*>(szT + (size_t)d * 4096 + base);
    __hip_bfloat16* yp = y + base * 2048 + d;
    const bool s0 = (s == 0);

    for (int t = 0; t < T_CHUNK / 8; ++t) {
        const short8 dv = dp[t], uv = up[t], bv = bp[t], cv = cp[t];
        short8 zv;
        if (s0) zv = zp[t];
#pragma unroll
        for (int k = 0; k < 8; ++k) {
            const float dt = bf2f(dv[k]);
            const float uu = bf2f(uv[k]);
            const float Bv = bf2f(bv[k]);
            const float Cv = bf2f(cv[k]);
            const float dA = __expf(dt * As);
            h = fmaf(dA, h, dt * uu * Bv);
            float py = row16_sum(h * Cv);
            if (s0) {
                const float yy = (py + uu * Dv) * bf2f(zv[k]);
                yp[(size_t)(t * 8 + k) * 2048] = __float2bfloat16(yy);
            }
        }
    }
}

extern "C" void kernel_launch(void* const* d_in, const int* in_sizes, int n_in,
                              void* d_out, int out_size, void* d_ws, size_t ws_size,
                              hipStream_t stream)
{
    const float* x          = (const float*)d_in[0];
    const float* in_proj_w  = (const float*)d_in[1];
    const float* conv_w     = (const float*)d_in[2];
    const float* conv_b     = (const float*)d_in[3];
    const float* x_proj_w   = (const float*)d_in[4];
    const float* dt_proj_w  = (const float*)d_in[5];
    const float* dt_proj_b  = (const float*)d_in[6];
    const float* A_log      = (const float*)d_in[7];
    const float* Dw         = (const float*)d_in[8];
    const float* out_proj_w = (const float*)d_in[9];
    const float* norm_w     = (const float*)d_in[10];
    const float* norm_b     = (const float*)d_in[11];

    float* out = (float*)d_out;
    float* res = out + 4194304;
    char* ws = (char*)d_ws;
    // Region A [0, 8.39M): h (dead after gemm1) -> P/S/Hinit + xdblT
    __hip_bfloat16* h      = (__hip_bfloat16*)(ws);                      // 8,388,608 B
    float*          Pbuf   = (float*)(ws);                               // 2M
    float*          Sbuf   = (float*)(ws + 2097152);                     // 2M
    float*          Hinit  = (float*)(ws + 4194304);                     // 2M
    __hip_bfloat16* xdblT  = (__hip_bfloat16*)(ws + 6291456);            // 96x4096x2 = 786,432 B (ends 7,077,888)
    // Region B [8.39M, 41.9M): xz (dead after conv_z) -> dtT + y
    __hip_bfloat16* xz     = (__hip_bfloat16*)(ws + 8388608);            // 32M
    __hip_bfloat16* dtT    = (__hip_bfloat16*)(ws + 8388608);            // 16M
    __hip_bfloat16* y      = (__hip_bfloat16*)(ws + 25165824);           // 16M
    // Region C/D
    __hip_bfloat16* uT     = (__hip_bfloat16*)(ws + 41943040);           // 16M
    __hip_bfloat16* szT    = (__hip_bfloat16*)(ws + 58720256);           // 16M (ends 75,497,472)

    // 1. LayerNorm + residual
    ln_res_kernel<<<4096, 256, 0, stream>>>(x, norm_w, norm_b, h, res);
    // 2. xz = h @ in_proj_w^T   (4096x4096x1024)
    gemm_bt<__hip_bfloat16><<<dim3(32, 32), 256, 0, stream>>>(h, in_proj_w, xz, 4096, 1024, 1024, 1024, 4096);
    // 3. uT = silu(conv(xz[:, :2048]))^T ; szT = silu(xz[:, 2048:])^T    [xz dead after]
    conv_z_kernel<<<dim3(64, 64), 256, 0, stream>>>(xz, conv_w, conv_b, uT, szT);
    // 4. xdblT = x_proj_w @ uT   (96 x 4096, K=2048)
    xproj_kernel<<<dim3(24, 16), 256, 0, stream>>>(uT, x_proj_w, xdblT);
    // 5. dtT = softplus(dt_low @ dt_proj_w^T + b)^T  (reads xdblT rows 0..63)
    gemm_dt<<<dim3(32, 16), 256, 0, stream>>>(xdblT, dt_proj_w, dt_proj_b, dtT);
    // 6. chunked scan
    scan_phase1<<<256 * G_CHUNKS, 256, 0, stream>>>(dtT, uT, xdblT, A_log, Pbuf, Sbuf);
    scan_phase2<<<256, 256, 0, stream>>>(Pbuf, Sbuf, Hinit);
    scan_phase3<<<256 * G_CHUNKS, 256, 0, stream>>>(dtT, uT, xdblT, szT, A_log, Dw, Hinit, y);
    // 7. out = y @ out_proj_w^T  (4096x1024x2048) -> f32
    gemm_bt<float><<<dim3(32, 8), 256, 0, stream>>>(y, out_proj_w, out, 1024, 2048, 2048, 2048, 1024);
}

// Round 5
// 480.204 us; speedup vs baseline: 5.9586x; 1.1269x over previous
//
#include <hip/hip_runtime.h>
#include <hip/hip_bf16.h>

typedef __attribute__((ext_vector_type(8))) short short8;
typedef __attribute__((ext_vector_type(4))) float floatx4;

#define BM 128
#define BN 128
#define BK 64
#define LDS_PAD 24
#define LDS_STRIDE (BK + LDS_PAD)

#define G_CHUNKS 8
#define T_CHUNK 256

__device__ __forceinline__ float bf2f(short v) {
    return __builtin_bit_cast(float, ((unsigned)(unsigned short)v) << 16);
}
__device__ __forceinline__ unsigned short f2bfbits(float f) {
    return __builtin_bit_cast(unsigned short, __float2bfloat16(f));
}
// 16-lane (DPP row) rotate-reduce sum: every lane of each 16-lane row ends with the row sum.
__device__ __forceinline__ float row16_sum(float v) {
    v += __builtin_bit_cast(float, __builtin_amdgcn_update_dpp(0, __builtin_bit_cast(int, v), 0x121, 0xf, 0xf, true));
    v += __builtin_bit_cast(float, __builtin_amdgcn_update_dpp(0, __builtin_bit_cast(int, v), 0x122, 0xf, 0xf, true));
    v += __builtin_bit_cast(float, __builtin_amdgcn_update_dpp(0, __builtin_bit_cast(int, v), 0x124, 0xf, 0xf, true));
    v += __builtin_bit_cast(float, __builtin_amdgcn_update_dpp(0, __builtin_bit_cast(int, v), 0x128, 0xf, 0xf, true));
    return v;
}

// ---------------- GEMM (plain): C[m,n] = sum_k A[m,k]*W[n,k], A bf16, W f32 staged->bf16 ----------------
template <typename OUT_T>
__global__ __launch_bounds__(256) void gemm_bt(
    const __hip_bfloat16* __restrict__ A, const float* __restrict__ W,
    OUT_T* __restrict__ C, int N, int K, int lda, int ldw, int ldc)
{
    __shared__ __align__(16) __hip_bfloat16 As[BM * LDS_STRIDE];
    __shared__ __align__(16) __hip_bfloat16 Ws[BN * LDS_STRIDE];
    const int tid  = threadIdx.x;
    const int bm   = blockIdx.x * BM;
    const int bn   = blockIdx.y * BN;
    const int lane = tid & 63;
    const int wid  = tid >> 6;
    const int wm   = (wid >> 1) * 64;
    const int wn   = (wid & 1) * 64;
    const int l15  = lane & 15;
    const int quad = lane >> 4;

    floatx4 acc[4][4];
#pragma unroll
    for (int i = 0; i < 4; ++i)
#pragma unroll
        for (int j = 0; j < 4; ++j)
#pragma unroll
            for (int r = 0; r < 4; ++r) acc[i][j][r] = 0.f;

    const int lrow = tid >> 3;
    const int lcol = (tid & 7) * 8;

    for (int k0 = 0; k0 < K; k0 += BK) {
#pragma unroll
        for (int r = 0; r < 4; ++r) {
            const int row = r * 32 + lrow;
            const uint4 va = *reinterpret_cast<const uint4*>(A + (size_t)(bm + row) * lda + k0 + lcol);
            *reinterpret_cast<uint4*>(&As[row * LDS_STRIDE + lcol]) = va;
            const int n = bn + row;
            __align__(16) unsigned short wb[8];
            const float4 f0 = *reinterpret_cast<const float4*>(W + (size_t)n * ldw + k0 + lcol);
            const float4 f1 = *reinterpret_cast<const float4*>(W + (size_t)n * ldw + k0 + lcol + 4);
            wb[0] = f2bfbits(f0.x); wb[1] = f2bfbits(f0.y);
            wb[2] = f2bfbits(f0.z); wb[3] = f2bfbits(f0.w);
            wb[4] = f2bfbits(f1.x); wb[5] = f2bfbits(f1.y);
            wb[6] = f2bfbits(f1.z); wb[7] = f2bfbits(f1.w);
            *reinterpret_cast<uint4*>(&Ws[row * LDS_STRIDE + lcol]) = *reinterpret_cast<const uint4*>(wb);
        }
        __syncthreads();
#pragma unroll
        for (int kk = 0; kk < BK; kk += 32) {
            short8 af[4], bfr[4];
#pragma unroll
            for (int i = 0; i < 4; ++i)
                af[i] = *reinterpret_cast<const short8*>(&As[(wm + i * 16 + l15) * LDS_STRIDE + kk + quad * 8]);
#pragma unroll
            for (int j = 0; j < 4; ++j)
                bfr[j] = *reinterpret_cast<const short8*>(&Ws[(wn + j * 16 + l15) * LDS_STRIDE + kk + quad * 8]);
#pragma unroll
            for (int i = 0; i < 4; ++i)
#pragma unroll
                for (int j = 0; j < 4; ++j)
                    acc[i][j] = __builtin_amdgcn_mfma_f32_16x16x32_bf16(af[i], bfr[j], acc[i][j], 0, 0, 0);
        }
        __syncthreads();
    }

#pragma unroll
    for (int i = 0; i < 4; ++i) {
#pragma unroll
        for (int j = 0; j < 4; ++j) {
            const int col = bn + wn + j * 16 + l15;
#pragma unroll
            for (int r = 0; r < 4; ++r) {
                const int rowg = bm + wm + i * 16 + quad * 4 + r;
                if constexpr (sizeof(OUT_T) == 4)
                    C[(size_t)rowg * ldc + col] = acc[i][j][r];
                else
                    C[(size_t)rowg * ldc + col] = __float2bfloat16(acc[i][j][r]);
            }
        }
    }
}

// ---------------- dt GEMM: A from transposed layout AT[96,4096] (rows 0..63), softplus, output dtT[2048,4096] ----------------
__global__ __launch_bounds__(256) void gemm_dt(
    const __hip_bfloat16* __restrict__ AT, const float* __restrict__ W,
    const float* __restrict__ bias, __hip_bfloat16* __restrict__ CT)
{
    __shared__ __align__(16) __hip_bfloat16 As[BM * LDS_STRIDE];
    __shared__ __align__(16) __hip_bfloat16 Ws[BN * LDS_STRIDE];
    const int tid  = threadIdx.x;
    const int bm   = blockIdx.x * BM;
    const int bn   = blockIdx.y * BN;
    const int lane = tid & 63;
    const int wid  = tid >> 6;
    const int wm   = (wid >> 1) * 64;
    const int wn   = (wid & 1) * 64;
    const int l15  = lane & 15;
    const int quad = lane >> 4;

    {
        const int kk = tid >> 4;
        const int mc = (tid & 15) * 8;
#pragma unroll
        for (int p = 0; p < 4; ++p) {
            const int k = kk + p * 16;
            const short8 v = *reinterpret_cast<const short8*>(AT + (size_t)k * 4096 + bm + mc);
#pragma unroll
            for (int e = 0; e < 8; ++e)
                As[(mc + e) * LDS_STRIDE + k] = __builtin_bit_cast(__hip_bfloat16, (unsigned short)v[e]);
        }
    }
    {
        const int lrow = tid >> 3;
        const int lcol = (tid & 7) * 8;
#pragma unroll
        for (int r = 0; r < 4; ++r) {
            const int n = bn + r * 32 + lrow;
            __align__(16) unsigned short wb[8];
            const float4 f0 = *reinterpret_cast<const float4*>(W + (size_t)n * 64 + lcol);
            const float4 f1 = *reinterpret_cast<const float4*>(W + (size_t)n * 64 + lcol + 4);
            wb[0] = f2bfbits(f0.x); wb[1] = f2bfbits(f0.y);
            wb[2] = f2bfbits(f0.z); wb[3] = f2bfbits(f0.w);
            wb[4] = f2bfbits(f1.x); wb[5] = f2bfbits(f1.y);
            wb[6] = f2bfbits(f1.z); wb[7] = f2bfbits(f1.w);
            *reinterpret_cast<uint4*>(&Ws[(r * 32 + lrow) * LDS_STRIDE + lcol]) = *reinterpret_cast<const uint4*>(wb);
        }
    }
    __syncthreads();

    floatx4 acc[4][4];
#pragma unroll
    for (int i = 0; i < 4; ++i)
#pragma unroll
        for (int j = 0; j < 4; ++j)
#pragma unroll
            for (int r = 0; r < 4; ++r) acc[i][j][r] = 0.f;

#pragma unroll
    for (int kk = 0; kk < BK; kk += 32) {
        short8 af[4], bfr[4];
#pragma unroll
        for (int i = 0; i < 4; ++i)
            af[i] = *reinterpret_cast<const short8*>(&As[(wm + i * 16 + l15) * LDS_STRIDE + kk + quad * 8]);
#pragma unroll
        for (int j = 0; j < 4; ++j)
            bfr[j] = *reinterpret_cast<const short8*>(&Ws[(wn + j * 16 + l15) * LDS_STRIDE + kk + quad * 8]);
#pragma unroll
        for (int i = 0; i < 4; ++i)
#pragma unroll
            for (int j = 0; j < 4; ++j)
                acc[i][j] = __builtin_amdgcn_mfma_f32_16x16x32_bf16(af[i], bfr[j], acc[i][j], 0, 0, 0);
    }

#pragma unroll
    for (int i = 0; i < 4; ++i) {
#pragma unroll
        for (int j = 0; j < 4; ++j) {
            const int col = bn + wn + j * 16 + l15;
            const int rowg0 = bm + wm + i * 16 + quad * 4;
            const float bv = bias[col];
            __align__(8) unsigned short pk[4];
#pragma unroll
            for (int r = 0; r < 4; ++r) {
                float v = acc[i][j][r] + bv;
                v = (v > 20.f) ? v : log1pf(__expf(v));
                pk[r] = f2bfbits(v);
            }
            *reinterpret_cast<uint2*>(CT + (size_t)col * 4096 + rowg0) = *reinterpret_cast<const uint2*>(pk);
        }
    }
}

// ---------------- LayerNorm + residual ----------------
__global__ __launch_bounds__(256) void ln_res_kernel(
    const float* __restrict__ x,
    const float* __restrict__ nw, const float* __restrict__ nb,
    __hip_bfloat16* __restrict__ h, float* __restrict__ res)
{
    const int row = blockIdx.x;
    const int tid = threadIdx.x;
    const float* xr = x + (size_t)row * 1024;
    float v[4];
    float sum = 0.f, sumsq = 0.f;
#pragma unroll
    for (int i = 0; i < 4; ++i) {
        const float f = xr[tid + i * 256];
        v[i] = f; sum += f; sumsq += f * f;
    }
#pragma unroll
    for (int off = 32; off > 0; off >>= 1) {
        sum   += __shfl_down(sum, off);
        sumsq += __shfl_down(sumsq, off);
    }
    __shared__ float ssum[4], ssq[4];
    const int w = tid >> 6, lane = tid & 63;
    if (lane == 0) { ssum[w] = sum; ssq[w] = sumsq; }
    __syncthreads();
    sum   = ssum[0] + ssum[1] + ssum[2] + ssum[3];
    sumsq = ssq[0] + ssq[1] + ssq[2] + ssq[3];
    const float mu  = sum * (1.f / 1024.f);
    const float var = sumsq * (1.f / 1024.f) - mu * mu;
    const float rs  = rsqrtf(var + 1e-5f);
#pragma unroll
    for (int i = 0; i < 4; ++i) {
        const int c = tid + i * 256;
        const float hn = (v[i] - mu) * rs * nw[c] + nb[c];
        h[(size_t)row * 1024 + c]   = __float2bfloat16(hn);
        res[(size_t)row * 1024 + c] = v[i];
    }
}

// ---------------- conv(width4,causal)+SiLU -> uT[d,token]; silu(z) -> szT[d,token] ----------------
#define CDT 32
#define CRT 64
__global__ __launch_bounds__(256) void conv_z_kernel(
    const __hip_bfloat16* __restrict__ xz,
    const float* __restrict__ conv_w, const float* __restrict__ conv_b,
    __hip_bfloat16* __restrict__ uT, __hip_bfloat16* __restrict__ szT)
{
    __shared__ __hip_bfloat16 xin[67][CDT + 1];
    __shared__ __hip_bfloat16 zs[CRT][CDT + 1];
    const int d0 = blockIdx.x * CDT;
    const int r0 = blockIdx.y * CRT;
    const int tid = threadIdx.x;
    const int l0 = r0 & 2047;
#pragma unroll
    for (int i = 0; i < 9; ++i) {
        const int idx = i * 256 + tid;
        const int r = idx >> 5, dl = idx & 31;
        if (r < 67) {
            __hip_bfloat16 v = __float2bfloat16(0.f);
            if (l0 + r - 3 >= 0) v = xz[(size_t)(r0 + r - 3) * 4096 + d0 + dl];
            xin[r][dl] = v;
        }
    }
#pragma unroll
    for (int i = 0; i < 8; ++i) {
        const int idx = i * 256 + tid;
        const int r = idx >> 5, dl = idx & 31;
        const float zv = __bfloat162float(xz[(size_t)(r0 + r) * 4096 + 2048 + d0 + dl]);
        zs[r][dl] = __float2bfloat16(zv / (1.f + __expf(-zv)));
    }
    __syncthreads();
    const int dl = tid >> 3, r8 = (tid & 7) * 8;
    const int d = d0 + dl;
    const float w0 = conv_w[d * 4 + 0], w1 = conv_w[d * 4 + 1],
                w2 = conv_w[d * 4 + 2], w3 = conv_w[d * 4 + 3];
    const float bv = conv_b[d];
    __align__(16) unsigned short ub[8], zb[8];
#pragma unroll
    for (int rr = 0; rr < 8; ++rr) {
        const int lr = r8 + rr;
        float a = fmaf(__bfloat162float(xin[lr][dl]),     w0, bv);
        a = fmaf(__bfloat162float(xin[lr + 1][dl]), w1, a);
        a = fmaf(__bfloat162float(xin[lr + 2][dl]), w2, a);
        a = fmaf(__bfloat162float(xin[lr + 3][dl]), w3, a);
        ub[rr] = f2bfbits(a / (1.f + __expf(-a)));
        zb[rr] = __builtin_bit_cast(unsigned short, zs[lr][dl]);
    }
    *reinterpret_cast<uint4*>(uT  + (size_t)d * 4096 + r0 + r8) = *reinterpret_cast<const uint4*>(ub);
    *reinterpret_cast<uint4*>(szT + (size_t)d * 4096 + r0 + r8) = *reinterpret_cast<const uint4*>(zb);
}

// ---------------- x_proj, split-K ----------------
// WT[k][n] = W[n][k], f32.  96*2048 elements; write-coalesced.
__global__ __launch_bounds__(256) void wt_prep(const float* __restrict__ W, float* __restrict__ WT)
{
    const int idx = blockIdx.x * 256 + threadIdx.x;    // 196608
    const int k = idx / 96, n = idx - k * 96;
    WT[idx] = W[(size_t)n * 2048 + k];
}

// part[c][n][m] = sum_{k in chunk c} uT[k][m] * WT[k][n]
__global__ __launch_bounds__(256) void xproj_partial(
    const __hip_bfloat16* __restrict__ uT, const float* __restrict__ WT,
    float* __restrict__ part)
{
    const int m  = blockIdx.y * 256 + threadIdx.x;
    const int n0 = blockIdx.x * 4;      // 24 n-groups
    const int c  = blockIdx.z;          // 8 k-chunks of 256
    const int k0 = c * 256;
    const float* wt = WT + (size_t)k0 * 96 + n0;
    const __hip_bfloat16* up = uT + (size_t)k0 * 4096 + m;
    float a0 = 0.f, a1 = 0.f, a2 = 0.f, a3 = 0.f;
#pragma unroll 8
    for (int k = 0; k < 256; ++k) {
        const float uv = __bfloat162float(up[(size_t)k * 4096]);
        const float4 w = *reinterpret_cast<const float4*>(wt + (size_t)k * 96);
        a0 = fmaf(uv, w.x, a0);
        a1 = fmaf(uv, w.y, a1);
        a2 = fmaf(uv, w.z, a2);
        a3 = fmaf(uv, w.w, a3);
    }
    float* pp = part + ((size_t)c * 96 + n0) * 4096 + m;
    pp[0]        = a0;
    pp[4096]     = a1;
    pp[2 * 4096] = a2;
    pp[3 * 4096] = a3;
}

// xdblT[n][m] = bf16( sum_c part[c][n][m] )
__global__ __launch_bounds__(256) void xproj_reduce(
    const float* __restrict__ part, __hip_bfloat16* __restrict__ xdblT)
{
    const int idx = blockIdx.x * 256 + threadIdx.x;     // 96*1024 float4 groups
    const int n = idx >> 10;
    const int m4 = (idx & 1023) * 4;
    float4 s = make_float4(0.f, 0.f, 0.f, 0.f);
#pragma unroll
    for (int c = 0; c < 8; ++c) {
        const float4 p = *reinterpret_cast<const float4*>(part + ((size_t)c * 96 + n) * 4096 + m4);
        s.x += p.x; s.y += p.y; s.z += p.z; s.w += p.w;
    }
    __align__(8) unsigned short pk[4];
    pk[0] = f2bfbits(s.x); pk[1] = f2bfbits(s.y);
    pk[2] = f2bfbits(s.z); pk[3] = f2bfbits(s.w);
    *reinterpret_cast<uint2*>(xdblT + (size_t)n * 4096 + m4) = *reinterpret_cast<const uint2*>(pk);
}

// ---------------- chunked scan, transposed operands ----------------
__global__ __launch_bounds__(256) void scan_phase1(
    const __hip_bfloat16* __restrict__ dtT, const __hip_bfloat16* __restrict__ uT,
    const __hip_bfloat16* __restrict__ xdblT, const float* __restrict__ A_log,
    float* __restrict__ Pbuf, float* __restrict__ Sbuf)
{
    const int tid = threadIdx.x;
    const int s   = tid & 15;
    const int g   = tid >> 4;
    const int cb  = blockIdx.x & 255;
    const int c   = blockIdx.x >> 8;
    const int b   = cb >> 7;
    const int d   = (cb & 127) * 16 + g;

    const float As = -__expf(A_log[d * 16 + s]);
    const size_t base = (size_t)b * 2048 + c * T_CHUNK;
    const short8* dp = reinterpret_cast<const short8*>(dtT + (size_t)d * 4096 + base);
    const short8* up = reinterpret_cast<const short8*>(uT  + (size_t)d * 4096 + base);
    const short8* bp = reinterpret_cast<const short8*>(xdblT + (size_t)(64 + s) * 4096 + base);
    float P = 1.f, S = 0.f;
    for (int t = 0; t < T_CHUNK / 8; ++t) {
        const short8 dv = dp[t], uv = up[t], bv = bp[t];
#pragma unroll
        for (int k = 0; k < 8; ++k) {
            const float dt = bf2f(dv[k]);
            const float uu = bf2f(uv[k]);
            const float Bv = bf2f(bv[k]);
            const float dA = __expf(dt * As);
            P *= dA;
            S = fmaf(dA, S, dt * uu * Bv);
        }
    }
    const int q = ((b << 11) + d) * 16 + s;
    Pbuf[q * G_CHUNKS + c] = P;
    Sbuf[q * G_CHUNKS + c] = S;
}

__global__ __launch_bounds__(256) void scan_phase2(
    const float* __restrict__ Pbuf, const float* __restrict__ Sbuf,
    float* __restrict__ Hinit)
{
    const int q = blockIdx.x * 256 + threadIdx.x;
    float h = 0.f;
#pragma unroll
    for (int c = 0; c < G_CHUNKS; ++c) {
        Hinit[q * G_CHUNKS + c] = h;
        h = Pbuf[q * G_CHUNKS + c] * h + Sbuf[q * G_CHUNKS + c];
    }
}

__global__ __launch_bounds__(256) void scan_phase3(
    const __hip_bfloat16* __restrict__ dtT, const __hip_bfloat16* __restrict__ uT,
    const __hip_bfloat16* __restrict__ xdblT, const __hip_bfloat16* __restrict__ szT,
    const float* __restrict__ A_log, const float* __restrict__ Dw,
    const float* __restrict__ Hinit, __hip_bfloat16* __restrict__ y)
{
    const int tid = threadIdx.x;
    const int s   = tid & 15;
    const int g   = tid >> 4;
    const int cb  = blockIdx.x & 255;
    const int c   = blockIdx.x >> 8;
    const int b   = cb >> 7;
    const int d   = (cb & 127) * 16 + g;

    const float As = -__expf(A_log[d * 16 + s]);
    const float Dv = Dw[d];
    const int q = ((b << 11) + d) * 16 + s;
    float h = Hinit[q * G_CHUNKS + c];
    const size_t base = (size_t)b * 2048 + c * T_CHUNK;
    const short8* dp = reinterpret_cast<const short8*>(dtT + (size_t)d * 4096 + base);
    const short8* up = reinterpret_cast<const short8*>(uT  + (size_t)d * 4096 + base);
    const short8* bp = reinterpret_cast<const short8*>(xdblT + (size_t)(64 + s) * 4096 + base);
    const short8* cp = reinterpret_cast<const short8*>(xdblT + (size_t)(80 + s) * 4096 + base);
    const short8* zp = reinterpret_cast<const short8*>(szT + (size_t)d * 4096 + base);
    __hip_bfloat16* yp = y + base * 2048 + d;
    const bool s0 = (s == 0);

    for (int t = 0; t < T_CHUNK / 8; ++t) {
        const short8 dv = dp[t], uv = up[t], bv = bp[t], cv = cp[t];
        short8 zv;
        if (s0) zv = zp[t];
#pragma unroll
        for (int k = 0; k < 8; ++k) {
            const float dt = bf2f(dv[k]);
            const float uu = bf2f(uv[k]);
            const float Bv = bf2f(bv[k]);
            const float Cv = bf2f(cv[k]);
            const float dA = __expf(dt * As);
            h = fmaf(dA, h, dt * uu * Bv);
            float py = row16_sum(h * Cv);
            if (s0) {
                const float yy = (py + uu * Dv) * bf2f(zv[k]);
                yp[(size_t)(t * 8 + k) * 2048] = __float2bfloat16(yy);
            }
        }
    }
}

extern "C" void kernel_launch(void* const* d_in, const int* in_sizes, int n_in,
                              void* d_out, int out_size, void* d_ws, size_t ws_size,
                              hipStream_t stream)
{
    const float* x          = (const float*)d_in[0];
    const float* in_proj_w  = (const float*)d_in[1];
    const float* conv_w     = (const float*)d_in[2];
    const float* conv_b     = (const float*)d_in[3];
    const float* x_proj_w   = (const float*)d_in[4];
    const float* dt_proj_w  = (const float*)d_in[5];
    const float* dt_proj_b  = (const float*)d_in[6];
    const float* A_log      = (const float*)d_in[7];
    const float* Dw         = (const float*)d_in[8];
    const float* out_proj_w = (const float*)d_in[9];
    const float* norm_w     = (const float*)d_in[10];
    const float* norm_b     = (const float*)d_in[11];

    float* out = (float*)d_out;
    float* res = out + 4194304;
    char* ws = (char*)d_ws;
    // Region A [0, 8.39M): h (dead after gemm1). Then: WT (dead after xproj_partial),
    // then Pbuf/Sbuf/Hinit (scan) + xdblT.
    __hip_bfloat16* h      = (__hip_bfloat16*)(ws);                      // 8,388,608 B
    float*          WT     = (float*)(ws);                               // 786,432 B (dead before Pbuf written)
    float*          Pbuf   = (float*)(ws);                               // 2M
    float*          Sbuf   = (float*)(ws + 2097152);                     // 2M
    float*          Hinit  = (float*)(ws + 4194304);                     // 2M
    __hip_bfloat16* xdblT  = (__hip_bfloat16*)(ws + 6291456);            // 786,432 B
    // Region B [8.39M, 41.9M): xz (dead after conv_z) -> part (dead after reduce) -> dtT + y
    __hip_bfloat16* xz     = (__hip_bfloat16*)(ws + 8388608);            // 32M
    float*          part   = (float*)(ws + 8388608);                     // 8*96*4096*4 = 12.6M
    __hip_bfloat16* dtT    = (__hip_bfloat16*)(ws + 8388608);            // 16M
    __hip_bfloat16* y      = (__hip_bfloat16*)(ws + 25165824);           // 16M
    // Region C/D
    __hip_bfloat16* uT     = (__hip_bfloat16*)(ws + 41943040);           // 16M
    __hip_bfloat16* szT    = (__hip_bfloat16*)(ws + 58720256);           // 16M

    // 1. LayerNorm + residual
    ln_res_kernel<<<4096, 256, 0, stream>>>(x, norm_w, norm_b, h, res);
    // 2. xz = h @ in_proj_w^T   (4096x4096x1024)
    gemm_bt<__hip_bfloat16><<<dim3(32, 32), 256, 0, stream>>>(h, in_proj_w, xz, 4096, 1024, 1024, 1024, 4096);
    // 3. uT = silu(conv(xz[:, :2048]))^T ; szT = silu(xz[:, 2048:])^T    [xz dead after]
    conv_z_kernel<<<dim3(64, 64), 256, 0, stream>>>(xz, conv_w, conv_b, uT, szT);
    // 4. xdblT = x_proj_w @ uT   (96 x 4096, K=2048), split-K over 8 chunks
    wt_prep<<<768, 256, 0, stream>>>(x_proj_w, WT);
    xproj_partial<<<dim3(24, 16, 8), 256, 0, stream>>>(uT, WT, part);
    xproj_reduce<<<384, 256, 0, stream>>>(part, xdblT);
    // 5. dtT = softplus(dt_low @ dt_proj_w^T + b)^T  (reads xdblT rows 0..63)
    gemm_dt<<<dim3(32, 16), 256, 0, stream>>>(xdblT, dt_proj_w, dt_proj_b, dtT);
    // 6. chunked scan
    scan_phase1<<<256 * G_CHUNKS, 256, 0, stream>>>(dtT, uT, xdblT, A_log, Pbuf, Sbuf);
    scan_phase2<<<256, 256, 0, stream>>>(Pbuf, Sbuf, Hinit);
    scan_phase3<<<256 * G_CHUNKS, 256, 0, stream>>>(dtT, uT, xdblT, szT, A_log, Dw, Hinit, y);
    // 7. out = y @ out_proj_w^T  (4096x1024x2048) -> f32
    gemm_bt<float><<<dim3(32, 8), 256, 0, stream>>>(y, out_proj_w, out, 1024, 2048, 2048, 2048, 1024);
}

// Round 6
// 460.039 us; speedup vs baseline: 6.2198x; 1.0438x over previous
//
#include <hip/hip_runtime.h>
#include <hip/hip_bf16.h>

typedef __attribute__((ext_vector_type(8))) short short8;
typedef __attribute__((ext_vector_type(4))) float floatx4;

#define BM 128
#define BN 128
#define BK 64
#define LDS_PAD 24
#define LDS_STRIDE (BK + LDS_PAD)

#define G_CHUNKS 16
#define T_CHUNK 128

__device__ __forceinline__ float bf2f(short v) {
    return __builtin_bit_cast(float, ((unsigned)(unsigned short)v) << 16);
}
__device__ __forceinline__ unsigned short f2bfbits(float f) {
    return __builtin_bit_cast(unsigned short, __float2bfloat16(f));
}
// 8-lane group sum (groups = lanes 8g..8g+7): quad xor1 + quad xor2 + xor4.
__device__ __forceinline__ float grp8_sum(float v) {
    v += __builtin_bit_cast(float, __builtin_amdgcn_update_dpp(0, __builtin_bit_cast(int, v), 0xB1, 0xf, 0xf, true)); // quad_perm [1,0,3,2]
    v += __builtin_bit_cast(float, __builtin_amdgcn_update_dpp(0, __builtin_bit_cast(int, v), 0x4E, 0xf, 0xf, true)); // quad_perm [2,3,0,1]
    v += __shfl_xor(v, 4);
    return v;
}

// ---------------- GEMM (plain): C[m,n] = sum_k A[m,k]*W[n,k], A bf16, W f32 staged->bf16 ----------------
template <typename OUT_T>
__global__ __launch_bounds__(256) void gemm_bt(
    const __hip_bfloat16* __restrict__ A, const float* __restrict__ W,
    OUT_T* __restrict__ C, int N, int K, int lda, int ldw, int ldc)
{
    __shared__ __align__(16) __hip_bfloat16 As[BM * LDS_STRIDE];
    __shared__ __align__(16) __hip_bfloat16 Ws[BN * LDS_STRIDE];
    const int tid  = threadIdx.x;
    const int bm   = blockIdx.x * BM;
    const int bn   = blockIdx.y * BN;
    const int lane = tid & 63;
    const int wid  = tid >> 6;
    const int wm   = (wid >> 1) * 64;
    const int wn   = (wid & 1) * 64;
    const int l15  = lane & 15;
    const int quad = lane >> 4;

    floatx4 acc[4][4];
#pragma unroll
    for (int i = 0; i < 4; ++i)
#pragma unroll
        for (int j = 0; j < 4; ++j)
#pragma unroll
            for (int r = 0; r < 4; ++r) acc[i][j][r] = 0.f;

    const int lrow = tid >> 3;
    const int lcol = (tid & 7) * 8;

    for (int k0 = 0; k0 < K; k0 += BK) {
#pragma unroll
        for (int r = 0; r < 4; ++r) {
            const int row = r * 32 + lrow;
            const uint4 va = *reinterpret_cast<const uint4*>(A + (size_t)(bm + row) * lda + k0 + lcol);
            *reinterpret_cast<uint4*>(&As[row * LDS_STRIDE + lcol]) = va;
            const int n = bn + row;
            __align__(16) unsigned short wb[8];
            const float4 f0 = *reinterpret_cast<const float4*>(W + (size_t)n * ldw + k0 + lcol);
            const float4 f1 = *reinterpret_cast<const float4*>(W + (size_t)n * ldw + k0 + lcol + 4);
            wb[0] = f2bfbits(f0.x); wb[1] = f2bfbits(f0.y);
            wb[2] = f2bfbits(f0.z); wb[3] = f2bfbits(f0.w);
            wb[4] = f2bfbits(f1.x); wb[5] = f2bfbits(f1.y);
            wb[6] = f2bfbits(f1.z); wb[7] = f2bfbits(f1.w);
            *reinterpret_cast<uint4*>(&Ws[row * LDS_STRIDE + lcol]) = *reinterpret_cast<const uint4*>(wb);
        }
        __syncthreads();
#pragma unroll
        for (int kk = 0; kk < BK; kk += 32) {
            short8 af[4], bfr[4];
#pragma unroll
            for (int i = 0; i < 4; ++i)
                af[i] = *reinterpret_cast<const short8*>(&As[(wm + i * 16 + l15) * LDS_STRIDE + kk + quad * 8]);
#pragma unroll
            for (int j = 0; j < 4; ++j)
                bfr[j] = *reinterpret_cast<const short8*>(&Ws[(wn + j * 16 + l15) * LDS_STRIDE + kk + quad * 8]);
#pragma unroll
            for (int i = 0; i < 4; ++i)
#pragma unroll
                for (int j = 0; j < 4; ++j)
                    acc[i][j] = __builtin_amdgcn_mfma_f32_16x16x32_bf16(af[i], bfr[j], acc[i][j], 0, 0, 0);
        }
        __syncthreads();
    }

#pragma unroll
    for (int i = 0; i < 4; ++i) {
#pragma unroll
        for (int j = 0; j < 4; ++j) {
            const int col = bn + wn + j * 16 + l15;
#pragma unroll
            for (int r = 0; r < 4; ++r) {
                const int rowg = bm + wm + i * 16 + quad * 4 + r;
                if constexpr (sizeof(OUT_T) == 4)
                    C[(size_t)rowg * ldc + col] = acc[i][j][r];
                else
                    C[(size_t)rowg * ldc + col] = __float2bfloat16(acc[i][j][r]);
            }
        }
    }
}

// ---------------- dt GEMM: A from transposed layout AT[96,4096] (rows 0..63), softplus, output dtT[2048,4096] ----------------
__global__ __launch_bounds__(256) void gemm_dt(
    const __hip_bfloat16* __restrict__ AT, const float* __restrict__ W,
    const float* __restrict__ bias, __hip_bfloat16* __restrict__ CT)
{
    __shared__ __align__(16) __hip_bfloat16 As[BM * LDS_STRIDE];
    __shared__ __align__(16) __hip_bfloat16 Ws[BN * LDS_STRIDE];
    const int tid  = threadIdx.x;
    const int bm   = blockIdx.x * BM;
    const int bn   = blockIdx.y * BN;
    const int lane = tid & 63;
    const int wid  = tid >> 6;
    const int wm   = (wid >> 1) * 64;
    const int wn   = (wid & 1) * 64;
    const int l15  = lane & 15;
    const int quad = lane >> 4;

    {
        const int kk = tid >> 4;
        const int mc = (tid & 15) * 8;
#pragma unroll
        for (int p = 0; p < 4; ++p) {
            const int k = kk + p * 16;
            const short8 v = *reinterpret_cast<const short8*>(AT + (size_t)k * 4096 + bm + mc);
#pragma unroll
            for (int e = 0; e < 8; ++e)
                As[(mc + e) * LDS_STRIDE + k] = __builtin_bit_cast(__hip_bfloat16, (unsigned short)v[e]);
        }
    }
    {
        const int lrow = tid >> 3;
        const int lcol = (tid & 7) * 8;
#pragma unroll
        for (int r = 0; r < 4; ++r) {
            const int n = bn + r * 32 + lrow;
            __align__(16) unsigned short wb[8];
            const float4 f0 = *reinterpret_cast<const float4*>(W + (size_t)n * 64 + lcol);
            const float4 f1 = *reinterpret_cast<const float4*>(W + (size_t)n * 64 + lcol + 4);
            wb[0] = f2bfbits(f0.x); wb[1] = f2bfbits(f0.y);
            wb[2] = f2bfbits(f0.z); wb[3] = f2bfbits(f0.w);
            wb[4] = f2bfbits(f1.x); wb[5] = f2bfbits(f1.y);
            wb[6] = f2bfbits(f1.z); wb[7] = f2bfbits(f1.w);
            *reinterpret_cast<uint4*>(&Ws[(r * 32 + lrow) * LDS_STRIDE + lcol]) = *reinterpret_cast<const uint4*>(wb);
        }
    }
    __syncthreads();

    floatx4 acc[4][4];
#pragma unroll
    for (int i = 0; i < 4; ++i)
#pragma unroll
        for (int j = 0; j < 4; ++j)
#pragma unroll
            for (int r = 0; r < 4; ++r) acc[i][j][r] = 0.f;

#pragma unroll
    for (int kk = 0; kk < BK; kk += 32) {
        short8 af[4], bfr[4];
#pragma unroll
        for (int i = 0; i < 4; ++i)
            af[i] = *reinterpret_cast<const short8*>(&As[(wm + i * 16 + l15) * LDS_STRIDE + kk + quad * 8]);
#pragma unroll
        for (int j = 0; j < 4; ++j)
            bfr[j] = *reinterpret_cast<const short8*>(&Ws[(wn + j * 16 + l15) * LDS_STRIDE + kk + quad * 8]);
#pragma unroll
        for (int i = 0; i < 4; ++i)
#pragma unroll
            for (int j = 0; j < 4; ++j)
                acc[i][j] = __builtin_amdgcn_mfma_f32_16x16x32_bf16(af[i], bfr[j], acc[i][j], 0, 0, 0);
    }

#pragma unroll
    for (int i = 0; i < 4; ++i) {
#pragma unroll
        for (int j = 0; j < 4; ++j) {
            const int col = bn + wn + j * 16 + l15;
            const int rowg0 = bm + wm + i * 16 + quad * 4;
            const float bv = bias[col];
            __align__(8) unsigned short pk[4];
#pragma unroll
            for (int r = 0; r < 4; ++r) {
                float v = acc[i][j][r] + bv;
                v = (v > 20.f) ? v : log1pf(__expf(v));
                pk[r] = f2bfbits(v);
            }
            *reinterpret_cast<uint2*>(CT + (size_t)col * 4096 + rowg0) = *reinterpret_cast<const uint2*>(pk);
        }
    }
}

// ---------------- LayerNorm + residual ----------------
__global__ __launch_bounds__(256) void ln_res_kernel(
    const float* __restrict__ x,
    const float* __restrict__ nw, const float* __restrict__ nb,
    __hip_bfloat16* __restrict__ h, float* __restrict__ res)
{
    const int row = blockIdx.x;
    const int tid = threadIdx.x;
    const float* xr = x + (size_t)row * 1024;
    float v[4];
    float sum = 0.f, sumsq = 0.f;
#pragma unroll
    for (int i = 0; i < 4; ++i) {
        const float f = xr[tid + i * 256];
        v[i] = f; sum += f; sumsq += f * f;
    }
#pragma unroll
    for (int off = 32; off > 0; off >>= 1) {
        sum   += __shfl_down(sum, off);
        sumsq += __shfl_down(sumsq, off);
    }
    __shared__ float ssum[4], ssq[4];
    const int w = tid >> 6, lane = tid & 63;
    if (lane == 0) { ssum[w] = sum; ssq[w] = sumsq; }
    __syncthreads();
    sum   = ssum[0] + ssum[1] + ssum[2] + ssum[3];
    sumsq = ssq[0] + ssq[1] + ssq[2] + ssq[3];
    const float mu  = sum * (1.f / 1024.f);
    const float var = sumsq * (1.f / 1024.f) - mu * mu;
    const float rs  = rsqrtf(var + 1e-5f);
#pragma unroll
    for (int i = 0; i < 4; ++i) {
        const int c = tid + i * 256;
        const float hn = (v[i] - mu) * rs * nw[c] + nb[c];
        h[(size_t)row * 1024 + c]   = __float2bfloat16(hn);
        res[(size_t)row * 1024 + c] = v[i];
    }
}

// ---------------- conv(width4,causal)+SiLU -> uT[d,token]; silu(z) -> szT[d,token] ----------------
#define CDT 32
#define CRT 64
__global__ __launch_bounds__(256) void conv_z_kernel(
    const __hip_bfloat16* __restrict__ xz,
    const float* __restrict__ conv_w, const float* __restrict__ conv_b,
    __hip_bfloat16* __restrict__ uT, __hip_bfloat16* __restrict__ szT)
{
    __shared__ __hip_bfloat16 xin[67][CDT + 1];
    __shared__ __hip_bfloat16 zs[CRT][CDT + 1];
    const int d0 = blockIdx.x * CDT;
    const int r0 = blockIdx.y * CRT;
    const int tid = threadIdx.x;
    const int l0 = r0 & 2047;
#pragma unroll
    for (int i = 0; i < 9; ++i) {
        const int idx = i * 256 + tid;
        const int r = idx >> 5, dl = idx & 31;
        if (r < 67) {
            __hip_bfloat16 v = __float2bfloat16(0.f);
            if (l0 + r - 3 >= 0) v = xz[(size_t)(r0 + r - 3) * 4096 + d0 + dl];
            xin[r][dl] = v;
        }
    }
#pragma unroll
    for (int i = 0; i < 8; ++i) {
        const int idx = i * 256 + tid;
        const int r = idx >> 5, dl = idx & 31;
        const float zv = __bfloat162float(xz[(size_t)(r0 + r) * 4096 + 2048 + d0 + dl]);
        zs[r][dl] = __float2bfloat16(zv / (1.f + __expf(-zv)));
    }
    __syncthreads();
    const int dl = tid >> 3, r8 = (tid & 7) * 8;
    const int d = d0 + dl;
    const float w0 = conv_w[d * 4 + 0], w1 = conv_w[d * 4 + 1],
                w2 = conv_w[d * 4 + 2], w3 = conv_w[d * 4 + 3];
    const float bv = conv_b[d];
    __align__(16) unsigned short ub[8], zb[8];
#pragma unroll
    for (int rr = 0; rr < 8; ++rr) {
        const int lr = r8 + rr;
        float a = fmaf(__bfloat162float(xin[lr][dl]),     w0, bv);
        a = fmaf(__bfloat162float(xin[lr + 1][dl]), w1, a);
        a = fmaf(__bfloat162float(xin[lr + 2][dl]), w2, a);
        a = fmaf(__bfloat162float(xin[lr + 3][dl]), w3, a);
        ub[rr] = f2bfbits(a / (1.f + __expf(-a)));
        zb[rr] = __builtin_bit_cast(unsigned short, zs[lr][dl]);
    }
    *reinterpret_cast<uint4*>(uT  + (size_t)d * 4096 + r0 + r8) = *reinterpret_cast<const uint4*>(ub);
    *reinterpret_cast<uint4*>(szT + (size_t)d * 4096 + r0 + r8) = *reinterpret_cast<const uint4*>(zb);
}

// ---------------- x_proj, split-K ----------------
__global__ __launch_bounds__(256) void wt_prep(const float* __restrict__ W, float* __restrict__ WT)
{
    const int idx = blockIdx.x * 256 + threadIdx.x;    // 196608
    const int k = idx / 96, n = idx - k * 96;
    WT[idx] = W[(size_t)n * 2048 + k];
}

__global__ __launch_bounds__(256) void xproj_partial(
    const __hip_bfloat16* __restrict__ uT, const float* __restrict__ WT,
    float* __restrict__ part)
{
    const int m  = blockIdx.y * 256 + threadIdx.x;
    const int n0 = blockIdx.x * 4;
    const int c  = blockIdx.z;
    const int k0 = c * 256;
    const float* wt = WT + (size_t)k0 * 96 + n0;
    const __hip_bfloat16* up = uT + (size_t)k0 * 4096 + m;
    float a0 = 0.f, a1 = 0.f, a2 = 0.f, a3 = 0.f;
#pragma unroll 8
    for (int k = 0; k < 256; ++k) {
        const float uv = __bfloat162float(up[(size_t)k * 4096]);
        const float4 w = *reinterpret_cast<const float4*>(wt + (size_t)k * 96);
        a0 = fmaf(uv, w.x, a0);
        a1 = fmaf(uv, w.y, a1);
        a2 = fmaf(uv, w.z, a2);
        a3 = fmaf(uv, w.w, a3);
    }
    float* pp = part + ((size_t)c * 96 + n0) * 4096 + m;
    pp[0]        = a0;
    pp[4096]     = a1;
    pp[2 * 4096] = a2;
    pp[3 * 4096] = a3;
}

__global__ __launch_bounds__(256) void xproj_reduce(
    const float* __restrict__ part, __hip_bfloat16* __restrict__ xdblT)
{
    const int idx = blockIdx.x * 256 + threadIdx.x;
    const int n = idx >> 10;
    const int m4 = (idx & 1023) * 4;
    float4 s = make_float4(0.f, 0.f, 0.f, 0.f);
#pragma unroll
    for (int c = 0; c < 8; ++c) {
        const float4 p = *reinterpret_cast<const float4*>(part + ((size_t)c * 96 + n) * 4096 + m4);
        s.x += p.x; s.y += p.y; s.z += p.z; s.w += p.w;
    }
    __align__(8) unsigned short pk[4];
    pk[0] = f2bfbits(s.x); pk[1] = f2bfbits(s.y);
    pk[2] = f2bfbits(s.z); pk[3] = f2bfbits(s.w);
    *reinterpret_cast<uint2*>(xdblT + (size_t)n * 4096 + m4) = *reinterpret_cast<const uint2*>(pk);
}

// ---------------- chunked scan: 2 states/lane, 8 lanes/channel, 8 channels/wave ----------------
// blockIdx.x = c*128 + cb; cb -> b = cb>>6, d0 = (cb&63)*32; lane: sp = tid&7, g = tid>>3.
__global__ __launch_bounds__(256) void scan_phase1(
    const __hip_bfloat16* __restrict__ dtT, const __hip_bfloat16* __restrict__ uT,
    const __hip_bfloat16* __restrict__ xdblT, const float* __restrict__ A_log,
    __hip_bfloat16* __restrict__ Pbuf, __hip_bfloat16* __restrict__ Sbuf)
{
    const int tid = threadIdx.x;
    const int sp  = tid & 7;
    const int g   = tid >> 3;            // 0..31
    const int cb  = blockIdx.x & 127;
    const int c   = blockIdx.x >> 7;
    const int b   = cb >> 6;
    const int d   = (cb & 63) * 32 + g;

    const float l2e = 1.44269504f;
    const float As0 = -__expf(A_log[d * 16 + sp])     * l2e;
    const float As1 = -__expf(A_log[d * 16 + sp + 8]) * l2e;
    const size_t base = (size_t)b * 2048 + c * T_CHUNK;
    const short8* dp  = reinterpret_cast<const short8*>(dtT + (size_t)d * 4096 + base);
    const short8* up  = reinterpret_cast<const short8*>(uT  + (size_t)d * 4096 + base);
    const short8* b0p = reinterpret_cast<const short8*>(xdblT + (size_t)(64 + sp) * 4096 + base);
    const short8* b1p = reinterpret_cast<const short8*>(xdblT + (size_t)(72 + sp) * 4096 + base);
    float P0 = 1.f, P1 = 1.f, S0 = 0.f, S1 = 0.f;
    for (int t = 0; t < T_CHUNK / 8; ++t) {
        const short8 dv = dp[t], uv = up[t], bv0 = b0p[t], bv1 = b1p[t];
#pragma unroll
        for (int k = 0; k < 8; ++k) {
            const float dt  = bf2f(dv[k]);
            const float dtu = dt * bf2f(uv[k]);
            const float dA0 = exp2f(dt * As0);
            const float dA1 = exp2f(dt * As1);
            P0 *= dA0; P1 *= dA1;
            S0 = fmaf(dA0, S0, dtu * bf2f(bv0[k]));
            S1 = fmaf(dA1, S1, dtu * bf2f(bv1[k]));
        }
    }
    const size_t q0 = ((size_t)((b << 11) + d) << 4) + sp;
    Pbuf[q0 * G_CHUNKS + c]       = __float2bfloat16(P0);
    Pbuf[(q0 + 8) * G_CHUNKS + c] = __float2bfloat16(P1);
    Sbuf[q0 * G_CHUNKS + c]       = __float2bfloat16(S0);
    Sbuf[(q0 + 8) * G_CHUNKS + c] = __float2bfloat16(S1);
}

__global__ __launch_bounds__(256) void scan_phase2(
    const __hip_bfloat16* __restrict__ Pbuf, const __hip_bfloat16* __restrict__ Sbuf,
    __hip_bfloat16* __restrict__ Hinit)
{
    const size_t q = blockIdx.x * 256 + threadIdx.x;   // 65536
    float h = 0.f;
#pragma unroll
    for (int c = 0; c < G_CHUNKS; ++c) {
        Hinit[q * G_CHUNKS + c] = __float2bfloat16(h);
        h = __bfloat162float(Pbuf[q * G_CHUNKS + c]) * h + __bfloat162float(Sbuf[q * G_CHUNKS + c]);
    }
}

__global__ __launch_bounds__(256) void scan_phase3(
    const __hip_bfloat16* __restrict__ dtT, const __hip_bfloat16* __restrict__ uT,
    const __hip_bfloat16* __restrict__ xdblT, const __hip_bfloat16* __restrict__ szT,
    const float* __restrict__ A_log, const float* __restrict__ Dw,
    const __hip_bfloat16* __restrict__ Hinit, __hip_bfloat16* __restrict__ y)
{
    const int tid = threadIdx.x;
    const int sp  = tid & 7;
    const int g   = tid >> 3;
    const int cb  = blockIdx.x & 127;
    const int c   = blockIdx.x >> 7;
    const int b   = cb >> 6;
    const int d   = (cb & 63) * 32 + g;

    const float l2e = 1.44269504f;
    const float As0 = -__expf(A_log[d * 16 + sp])     * l2e;
    const float As1 = -__expf(A_log[d * 16 + sp + 8]) * l2e;
    const float Dv  = Dw[d];
    const size_t q0 = ((size_t)((b << 11) + d) << 4) + sp;
    float h0 = __bfloat162float(Hinit[q0 * G_CHUNKS + c]);
    float h1 = __bfloat162float(Hinit[(q0 + 8) * G_CHUNKS + c]);
    const size_t base = (size_t)b * 2048 + c * T_CHUNK;
    const short8* dp  = reinterpret_cast<const short8*>(dtT + (size_t)d * 4096 + base);
    const short8* up  = reinterpret_cast<const short8*>(uT  + (size_t)d * 4096 + base);
    const short8* b0p = reinterpret_cast<const short8*>(xdblT + (size_t)(64 + sp) * 4096 + base);
    const short8* b1p = reinterpret_cast<const short8*>(xdblT + (size_t)(72 + sp) * 4096 + base);
    const short8* c0p = reinterpret_cast<const short8*>(xdblT + (size_t)(80 + sp) * 4096 + base);
    const short8* c1p = reinterpret_cast<const short8*>(xdblT + (size_t)(88 + sp) * 4096 + base);
    const short8* zp  = reinterpret_cast<const short8*>(szT + (size_t)d * 4096 + base);
    __hip_bfloat16* yp = y + base * 2048 + d;
    const bool lead = (sp == 0);

    for (int t = 0; t < T_CHUNK / 8; ++t) {
        const short8 dv = dp[t], uv = up[t], bv0 = b0p[t], bv1 = b1p[t],
                     cv0 = c0p[t], cv1 = c1p[t], zv = zp[t];
#pragma unroll
        for (int k = 0; k < 8; ++k) {
            const float dt  = bf2f(dv[k]);
            const float uu  = bf2f(uv[k]);
            const float dtu = dt * uu;
            const float dA0 = exp2f(dt * As0);
            const float dA1 = exp2f(dt * As1);
            h0 = fmaf(dA0, h0, dtu * bf2f(bv0[k]));
            h1 = fmaf(dA1, h1, dtu * bf2f(bv1[k]));
            float py = fmaf(h1, bf2f(cv1[k]), h0 * bf2f(cv0[k]));
            py = grp8_sum(py);
            if (lead) {
                const float yy = (py + uu * Dv) * bf2f(zv[k]);
                yp[(size_t)(t * 8 + k) * 2048] = __float2bfloat16(yy);
            }
        }
    }
}

extern "C" void kernel_launch(void* const* d_in, const int* in_sizes, int n_in,
                              void* d_out, int out_size, void* d_ws, size_t ws_size,
                              hipStream_t stream)
{
    const float* x          = (const float*)d_in[0];
    const float* in_proj_w  = (const float*)d_in[1];
    const float* conv_w     = (const float*)d_in[2];
    const float* conv_b     = (const float*)d_in[3];
    const float* x_proj_w   = (const float*)d_in[4];
    const float* dt_proj_w  = (const float*)d_in[5];
    const float* dt_proj_b  = (const float*)d_in[6];
    const float* A_log      = (const float*)d_in[7];
    const float* Dw         = (const float*)d_in[8];
    const float* out_proj_w = (const float*)d_in[9];
    const float* norm_w     = (const float*)d_in[10];
    const float* norm_b     = (const float*)d_in[11];

    float* out = (float*)d_out;
    float* res = out + 4194304;
    char* ws = (char*)d_ws;
    // Region A [0, 8.39M): h (dead after gemm1) -> WT (dead after xproj_partial)
    //   -> Pb/Sb/Hinit (bf16, 2M each) + xdblT.
    __hip_bfloat16* h      = (__hip_bfloat16*)(ws);                      // 8,388,608 B
    float*          WT     = (float*)(ws);                               // 786,432 B
    __hip_bfloat16* Pbuf   = (__hip_bfloat16*)(ws);                      // 2M  (65536*16 bf16)
    __hip_bfloat16* Sbuf   = (__hip_bfloat16*)(ws + 2097152);            // 2M
    __hip_bfloat16* Hinit  = (__hip_bfloat16*)(ws + 4194304);            // 2M
    __hip_bfloat16* xdblT  = (__hip_bfloat16*)(ws + 6291456);            // 786,432 B
    // Region B [8.39M, 41.9M): xz (dead after conv_z) -> part (dead after reduce) -> dtT + y
    __hip_bfloat16* xz     = (__hip_bfloat16*)(ws + 8388608);            // 32M
    float*          part   = (float*)(ws + 8388608);                     // 12.6M
    __hip_bfloat16* dtT    = (__hip_bfloat16*)(ws + 8388608);            // 16M
    __hip_bfloat16* y      = (__hip_bfloat16*)(ws + 25165824);           // 16M
    // Region C/D
    __hip_bfloat16* uT     = (__hip_bfloat16*)(ws + 41943040);           // 16M
    __hip_bfloat16* szT    = (__hip_bfloat16*)(ws + 58720256);           // 16M

    // 1. LayerNorm + residual
    ln_res_kernel<<<4096, 256, 0, stream>>>(x, norm_w, norm_b, h, res);
    // 2. xz = h @ in_proj_w^T   (4096x4096x1024)
    gemm_bt<__hip_bfloat16><<<dim3(32, 32), 256, 0, stream>>>(h, in_proj_w, xz, 4096, 1024, 1024, 1024, 4096);
    // 3. uT = silu(conv(xz[:, :2048]))^T ; szT = silu(xz[:, 2048:])^T    [xz dead after]
    conv_z_kernel<<<dim3(64, 64), 256, 0, stream>>>(xz, conv_w, conv_b, uT, szT);
    // 4. xdblT = x_proj_w @ uT   (96 x 4096, K=2048), split-K over 8 chunks
    wt_prep<<<768, 256, 0, stream>>>(x_proj_w, WT);
    xproj_partial<<<dim3(24, 16, 8), 256, 0, stream>>>(uT, WT, part);
    xproj_reduce<<<384, 256, 0, stream>>>(part, xdblT);
    // 5. dtT = softplus(dt_low @ dt_proj_w^T + b)^T
    gemm_dt<<<dim3(32, 16), 256, 0, stream>>>(xdblT, dt_proj_w, dt_proj_b, dtT);
    // 6. chunked scan (G=16, T=128)
    scan_phase1<<<128 * G_CHUNKS, 256, 0, stream>>>(dtT, uT, xdblT, A_log, Pbuf, Sbuf);
    scan_phase2<<<256, 256, 0, stream>>>(Pbuf, Sbuf, Hinit);
    scan_phase3<<<128 * G_CHUNKS, 256, 0, stream>>>(dtT, uT, xdblT, szT, A_log, Dw, Hinit, y);
    // 7. out = y @ out_proj_w^T  (4096x1024x2048) -> f32
    gemm_bt<float><<<dim3(32, 8), 256, 0, stream>>>(y, out_proj_w, out, 1024, 2048, 2048, 2048, 1024);
}